// Round 3
// baseline (956.680 us; speedup 1.0000x reference)
//
#include <hip/hip_runtime.h>
#include <hip/hip_cooperative_groups.h>
#include <hip/hip_fp16.h>
#include <math.h>

namespace cg = cooperative_groups;

#define THREADS 256
#define XS_STRIDE 68

// ===================== cooperative mega-kernel =====================
// Phases (grid.sync between): 0 zero degs  1 degree histograms (global atomics)
// 2 block-scan rowStart (atomic base claim; CSR row order is irrelevant)
// 3 CSR fill (atomic cursor) || layer-1 GEMM   4/5 agg+GEMM   6 agg+FC
struct GP {
    const float* x; const int* src; const int* dst;
    const float* W1; const float* b1; const float* W2; const float* b2;
    const float* W3; const float* b3; const float* Wfc; const float* bfc;
    float* out;
    int* deg_s; int* deg_d; int* rowStart; int* cur;
    float* ns; float* nd; int* col;
    __half* bufH; __half* bufH2; unsigned int* counter;
    int N; int E;
};

__global__ __launch_bounds__(256, 4) void k_all(GP p) {
    cg::grid_group grid = cg::this_grid();
    __shared__ float Xs[64 * XS_STRIDE];
    __shared__ float Ws[4096];
    __shared__ float Wb[16];
    __shared__ int baseSh;

    const int tid = threadIdx.x;
    const int bid = blockIdx.x;
    const int nb  = gridDim.x;
    const int gtid = bid * 256 + tid;
    const int gstride = nb * 256;
    const int N = p.N, E = p.E;
    const int ntiles = (N + 63) >> 6;

    // ---- phase 0: zero degree arrays + counter
    for (int i = gtid; i < N; i += gstride) { p.deg_s[i] = 0; p.deg_d[i] = 0; }
    if (gtid == 0) *p.counter = 0u;
    __threadfence();
    grid.sync();

    // ---- phase 1: degree histograms via device-scope atomics
    for (int e = gtid; e < E; e += gstride) {
        atomicAdd(&p.deg_s[p.src[e]], 1);
        atomicAdd(&p.deg_d[p.dst[e]], 1);
    }
    __threadfence();
    grid.sync();

    // ---- phase 2: per-256-node block scan, row base claimed atomically
    {
        int nvb = (N + 255) >> 8;
        for (int vb = bid; vb < nvb; vb += nb) {
            int i = (vb << 8) + tid;
            int d = (i < N) ? p.deg_d[i] : 0;
            int* sd = (int*)Xs;
            sd[tid] = d;
            __syncthreads();
            for (int off = 1; off < 256; off <<= 1) {
                int xv = (tid >= off) ? sd[tid - off] : 0;
                __syncthreads();
                sd[tid] += xv;
                __syncthreads();
            }
            int incl = sd[tid];
            int excl = incl - d;
            if (tid == 255) baseSh = (int)atomicAdd(p.counter, (unsigned int)incl);
            __syncthreads();
            int base = baseSh;
            if (i < N) {
                int rs = base + excl;
                p.rowStart[i] = rs;
                p.cur[i] = rs;
                p.nd[i] = d ? 1.0f / sqrtf((float)d) : 0.0f;
                int s = p.deg_s[i];
                p.ns[i] = s ? 1.0f / sqrtf((float)s) : 0.0f;
            }
            __syncthreads();
        }
    }
    __threadfence();
    grid.sync();

    // shared helpers -----------------------------------------------------
    auto mma_store = [&](__half* Hout, int rowBase) {
        int tc = tid & 15, tr = tid >> 4;
        int c0 = tc * 4, r0 = tr * 4;
        float acc[4][4] = {};
#pragma unroll 2
        for (int k = 0; k < 64; k += 4) {
            float4 wv[4];
#pragma unroll
            for (int kk = 0; kk < 4; kk++)
                wv[kk] = *((const float4*)&Ws[(k + kk) * 64 + c0]);
#pragma unroll
            for (int j = 0; j < 4; j++) {
                float4 xv = *((const float4*)&Xs[(r0 + j) * XS_STRIDE + k]);
                acc[j][0] += xv.x * wv[0].x; acc[j][1] += xv.x * wv[0].y;
                acc[j][2] += xv.x * wv[0].z; acc[j][3] += xv.x * wv[0].w;
                acc[j][0] += xv.y * wv[1].x; acc[j][1] += xv.y * wv[1].y;
                acc[j][2] += xv.y * wv[1].z; acc[j][3] += xv.y * wv[1].w;
                acc[j][0] += xv.z * wv[2].x; acc[j][1] += xv.z * wv[2].y;
                acc[j][2] += xv.z * wv[2].z; acc[j][3] += xv.z * wv[2].w;
                acc[j][0] += xv.w * wv[3].x; acc[j][1] += xv.w * wv[3].y;
                acc[j][2] += xv.w * wv[3].z; acc[j][3] += xv.w * wv[3].w;
            }
        }
#pragma unroll
        for (int j = 0; j < 4; j++) {
            int row = rowBase + r0 + j;
            if (row < N) {
                __half2 h01 = __floats2half2_rn(acc[j][0], acc[j][1]);
                __half2 h23 = __floats2half2_rn(acc[j][2], acc[j][3]);
                uint2 pk;
                pk.x = *(unsigned int*)&h01;
                pk.y = *(unsigned int*)&h23;
                *((uint2*)(Hout + (size_t)row * 64 + c0)) = pk;
            }
        }
    };

    // agg phase A: 8 nodes in flight per wave; fills 16 Xs rows per wave
    auto aggA = [&](const uint4* H4, const float* bias, bool prescale, int rowBase) {
        int wave = tid >> 6;
        int lane = tid & 63;
        int g = lane >> 3;
        int l = lane & 7;
        float4 bv0 = *((const float4*)&bias[l * 8]);
        float4 bv1 = *((const float4*)&bias[l * 8 + 4]);

        int nodeA = rowBase + wave * 16 + g;
        int nodeB = nodeA + 8;
        int stA = 0, nA = 0; float nvA = 0.f, nsA = 0.f;
        if (nodeA < N) {
            stA = p.rowStart[nodeA]; nA = p.deg_d[nodeA]; nvA = p.nd[nodeA];
            if (prescale) nsA = p.ns[nodeA];
        }
        int stB = 0, nB = 0; float nvB = 0.f, nsB = 0.f;
        if (nodeB < N) {
            stB = p.rowStart[nodeB]; nB = p.deg_d[nodeB]; nvB = p.nd[nodeB];
            if (prescale) nsB = p.ns[nodeB];
        }
        int idxA = (l < nA) ? p.col[stA + l] : 0;
        int idxB = (l < nB) ? p.col[stB + l] : 0;
        int mA = nA, mB = nB;
#pragma unroll
        for (int d = 8; d <= 32; d <<= 1) {
            int tA = __shfl_xor(mA, d); mA = mA > tA ? mA : tA;
            int tB = __shfl_xor(mB, d); mB = mB > tB ? mB : tB;
        }

        auto runNode = [&](int start, int n, int m, int idx, float nv, float nsv,
                           bool vn, int row) {
            float acc[8] = {0.f,0.f,0.f,0.f,0.f,0.f,0.f,0.f};
            for (int j0 = 0; j0 < m; j0 += 8) {
                int idxn = ((j0 + 8 + l) < n) ? p.col[start + j0 + 8 + l] : 0;
#pragma unroll
                for (int jj = 0; jj < 8; jj++) {
                    int s = __shfl(idx, (g << 3) + jj);
                    if (j0 + jj < n) {
                        uint4 v = H4[(size_t)s * 8 + l];
                        float2 f0 = __half22float2(*(__half2*)&v.x);
                        float2 f1 = __half22float2(*(__half2*)&v.y);
                        float2 f2 = __half22float2(*(__half2*)&v.z);
                        float2 f3 = __half22float2(*(__half2*)&v.w);
                        acc[0] += f0.x; acc[1] += f0.y; acc[2] += f1.x; acc[3] += f1.y;
                        acc[4] += f2.x; acc[5] += f2.y; acc[6] += f3.x; acc[7] += f3.y;
                    }
                }
                idx = idxn;
            }
            float4 o0, o1;
            o0.x = tanhf(acc[0] * nv + bv0.x);
            o0.y = tanhf(acc[1] * nv + bv0.y);
            o0.z = tanhf(acc[2] * nv + bv0.z);
            o0.w = tanhf(acc[3] * nv + bv0.w);
            o1.x = tanhf(acc[4] * nv + bv1.x);
            o1.y = tanhf(acc[5] * nv + bv1.y);
            o1.z = tanhf(acc[6] * nv + bv1.z);
            o1.w = tanhf(acc[7] * nv + bv1.w);
            if (prescale) {
                o0.x *= nsv; o0.y *= nsv; o0.z *= nsv; o0.w *= nsv;
                o1.x *= nsv; o1.y *= nsv; o1.z *= nsv; o1.w *= nsv;
            }
            if (!vn) {
                o0 = make_float4(0.f,0.f,0.f,0.f);
                o1 = make_float4(0.f,0.f,0.f,0.f);
            }
            *((float4*)&Xs[row * XS_STRIDE + l * 8])     = o0;
            *((float4*)&Xs[row * XS_STRIDE + l * 8 + 4]) = o1;
        };
        runNode(stA, nA, mA, idxA, nvA, nsA, nodeA < N, wave * 16 + g);
        runNode(stB, nB, mB, idxB, nvB, nsB, nodeB < N, wave * 16 + 8 + g);
    };

    // ---- phase 3: CSR fill (atomic cursor) then layer-1 GEMM
    for (int e = gtid; e < E; e += gstride) {
        int d_ = p.dst[e];
        int pos = atomicAdd(&p.cur[d_], 1);
        p.col[pos] = p.src[e];
    }
    for (int t = bid; t < ntiles; t += nb) {
        int rowBase = t << 6;
        for (int i = tid; i < 1024; i += 256)
            ((float4*)Ws)[i] = ((const float4*)p.W1)[i];
        for (int i = tid; i < 1024; i += 256) {
            int r = i >> 4, k4 = i & 15;
            int row = rowBase + r;
            float4 v = make_float4(0.f,0.f,0.f,0.f);
            if (row < N) {
                v = ((const float4*)p.x)[(size_t)row * 16 + k4];
                float nv = p.ns[row];
                v.x *= nv; v.y *= nv; v.z *= nv; v.w *= nv;
            }
            *((float4*)&Xs[r * XS_STRIDE + (k4 << 2)]) = v;
        }
        __syncthreads();
        mma_store(p.bufH, rowBase);
        __syncthreads();
    }
    __threadfence();
    grid.sync();

    // ---- phase 4: agg layer 1 (H1 -> H2)
    for (int t = bid; t < ntiles; t += nb) {
        int rowBase = t << 6;
        for (int i = tid; i < 1024; i += 256)
            ((float4*)Ws)[i] = ((const float4*)p.W2)[i];
        aggA((const uint4*)p.bufH, p.b1, true, rowBase);
        __syncthreads();
        mma_store(p.bufH2, rowBase);
        __syncthreads();
    }
    __threadfence();
    grid.sync();

    // ---- phase 5: agg layer 2 (H2 -> H3)
    for (int t = bid; t < ntiles; t += nb) {
        int rowBase = t << 6;
        for (int i = tid; i < 1024; i += 256)
            ((float4*)Ws)[i] = ((const float4*)p.W3)[i];
        aggA((const uint4*)p.bufH2, p.b2, true, rowBase);
        __syncthreads();
        mma_store(p.bufH, rowBase);
        __syncthreads();
    }
    __threadfence();
    grid.sync();

    // ---- phase 6: agg layer 3 + FC
    for (int t = bid; t < ntiles; t += nb) {
        int rowBase = t << 6;
        for (int i = tid; i < 640; i += 256) {   // Ws[c*64+k] = Wfc[k][c]
            int k = i / 10, c = i - k * 10;
            Ws[c * 64 + k] = p.Wfc[i];
        }
        if (tid < 10) Wb[tid] = p.bfc[tid];
        aggA((const uint4*)p.bufH, p.b3, false, rowBase);
        __syncthreads();
        for (int idx = tid; idx < 640; idx += 256) {
            int ln = idx / 10;
            int cl = idx - ln * 10;
            float acc = Wb[cl];
#pragma unroll
            for (int k = 0; k < 64; k += 4) {
                float4 xv = *((const float4*)&Xs[ln * XS_STRIDE + k]);
                float4 wv = *((const float4*)&Ws[cl * 64 + k]);
                acc += xv.x * wv.x + xv.y * wv.y + xv.z * wv.z + xv.w * wv.w;
            }
            int row = rowBase + ln;
            if (row < N) p.out[(size_t)row * 10 + cl] = acc;
        }
        __syncthreads();
    }
}

// ===================== fallback: proven round-2 pipeline =====================
#define CHUNK_SHIFT 15
#define CHUNK (1 << CHUNK_SHIFT)
#define LDS_WORDS 12500
#define MAXB 16

__global__ __launch_bounds__(1024)
void k_hist(const int* __restrict__ src, const int* __restrict__ dst,
            unsigned int* __restrict__ partS, unsigned int* __restrict__ partD,
            unsigned char* __restrict__ rank, unsigned int* __restrict__ counter,
            int E, int P, int words) {
    __shared__ unsigned int hist[LDS_WORDS];
    if (blockIdx.x == 0 && threadIdx.x == 0) *counter = 0u;
    int isSrc = (blockIdx.x >= (unsigned)P);
    int b = isSrc ? (blockIdx.x - P) : blockIdx.x;
    int tid = threadIdx.x;
    for (int w = tid; w < words; w += 1024) hist[w] = 0u;
    __syncthreads();
    int start = b << CHUNK_SHIFT;
    int end = start + CHUNK; if (end > E) end = E;
    if (isSrc) {
        for (int e = start + tid; e < end; e += 1024) {
            int s = src[e];
            atomicAdd(&hist[s >> 2], 1u << ((s & 3) * 8));
        }
    } else {
        for (int e = start + tid; e < end; e += 1024) {
            int d = dst[e];
            unsigned int old = atomicAdd(&hist[d >> 2], 1u << ((d & 3) * 8));
            rank[e] = (unsigned char)((old >> ((d & 3) * 8)) & 0xFFu);
        }
    }
    __syncthreads();
    unsigned int* part = isSrc ? partS : partD;
    for (int w = tid; w < words; w += 1024)
        part[(size_t)b * words + w] = hist[w];
}

__global__ __launch_bounds__(THREADS)
void k_pre(const unsigned int* __restrict__ partS,
           const unsigned int* __restrict__ partD,
           unsigned int* __restrict__ prefD,
           int* __restrict__ deg_d, float* __restrict__ ns, float* __restrict__ nd,
           int* __restrict__ rp, int* __restrict__ bsum,
           unsigned int* __restrict__ counter,
           int P, int words, int N) {
    __shared__ unsigned int qsD[4][64];
    __shared__ unsigned int qsS[4][64];
    int t = threadIdx.x;
    int widx = t & 63;
    int q = t >> 6;
    int w = blockIdx.x * 64 + widx;
    bool valid = (w < words);
    int per = (P + 3) >> 2;
    int blo = q * per;
    int cnt = P - blo; if (cnt > per) cnt = per; if (cnt < 0) cnt = 0;
    unsigned int vD[MAXB];
    unsigned int runD = 0, runS = 0;
#pragma unroll
    for (int bb = 0; bb < MAXB; bb++) {
        unsigned int vd = 0, vs = 0;
        if (bb < cnt && valid) {
            size_t off = (size_t)(blo + bb) * words + w;
            vd = partD[off];
            vs = partS[off];
        }
        vD[bb] = vd;
        runD += vd;
        runS += vs;
    }
    qsD[q][widx] = runD;
    qsS[q][widx] = runS;
    __syncthreads();
    unsigned int baseD = 0, totD = 0, totS = 0;
#pragma unroll
    for (int qq = 0; qq < 4; qq++) {
        unsigned int xd = qsD[qq][widx];
        unsigned int xs = qsS[qq][widx];
        if (qq < q) baseD += xd;
        totD += xd;
        totS += xs;
    }
    unsigned int pref = baseD;
#pragma unroll
    for (int bb = 0; bb < MAXB; bb++) {
        if (bb < cnt && valid)
            prefD[(size_t)(blo + bb) * words + w] = pref;
        pref += vD[bb];
    }
    if (q == 0) {
        int b0 = (int)(totD & 0xFFu), b1 = (int)((totD >> 8) & 0xFFu),
            b2 = (int)((totD >> 16) & 0xFFu), b3 = (int)((totD >> 24) & 0xFFu);
        int wsum = b0 + b1 + b2 + b3;
        int incl = wsum;
#pragma unroll
        for (int off = 1; off < 64; off <<= 1) {
            int y = __shfl_up(incl, off);
            if (widx >= off) incl += y;
        }
        int excl = incl - wsum;
        int btot = __shfl(incl, 63);
        if (widx == 0)
            bsum[blockIdx.x] = (int)atomicAdd(counter, (unsigned int)btot);
        if (valid) {
            int s0 = (int)(totS & 0xFFu), s1 = (int)((totS >> 8) & 0xFFu),
                s2 = (int)((totS >> 16) & 0xFFu), s3 = (int)((totS >> 24) & 0xFFu);
            int4 dv; dv.x = b0; dv.y = b1; dv.z = b2; dv.w = b3;
            *(int4*)&deg_d[(size_t)4 * w] = dv;
            float4 ndv;
            ndv.x = b0 ? 1.0f / sqrtf((float)b0) : 0.0f;
            ndv.y = b1 ? 1.0f / sqrtf((float)b1) : 0.0f;
            ndv.z = b2 ? 1.0f / sqrtf((float)b2) : 0.0f;
            ndv.w = b3 ? 1.0f / sqrtf((float)b3) : 0.0f;
            *(float4*)&nd[(size_t)4 * w] = ndv;
            float4 nsv;
            nsv.x = s0 ? 1.0f / sqrtf((float)s0) : 0.0f;
            nsv.y = s1 ? 1.0f / sqrtf((float)s1) : 0.0f;
            nsv.z = s2 ? 1.0f / sqrtf((float)s2) : 0.0f;
            nsv.w = s3 ? 1.0f / sqrtf((float)s3) : 0.0f;
            *(float4*)&ns[(size_t)4 * w] = nsv;
            int4 rv; rv.x = excl; rv.y = excl + b0;
            rv.z = excl + b0 + b1; rv.w = excl + b0 + b1 + b2;
            *(int4*)&rp[(size_t)4 * w] = rv;
        }
    }
}

__global__ __launch_bounds__(256, 4)
void k_fill_gemm(const int* __restrict__ src, const int* __restrict__ dst,
                 const int* __restrict__ rp, const int* __restrict__ bsum,
                 const unsigned char* __restrict__ rank,
                 const unsigned int* __restrict__ prefD,
                 int* __restrict__ col, int E, int words, int gFill,
                 const float* __restrict__ X, const float* __restrict__ norm,
                 const float* __restrict__ W, __half* __restrict__ H, int N) {
    __shared__ float Xs[64 * XS_STRIDE];
    __shared__ float Ws[64 * 64];
    int tid = threadIdx.x;
    if ((int)blockIdx.x < gFill) {
        int e = blockIdx.x * 256 + tid;
        if (e < E) {
            int d = dst[e];
            int b = e >> CHUNK_SHIFT;
            unsigned int pk = prefD[(size_t)b * words + (d >> 2)];
            int pref = (int)((pk >> ((d & 3) * 8)) & 0xFFu);
            col[rp[d] + bsum[d >> 8] + pref + (int)rank[e]] = src[e];
        }
        return;
    }
    int rowBase = ((int)blockIdx.x - gFill) * 64;
    for (int i = tid; i < 1024; i += 256)
        ((float4*)Ws)[i] = ((const float4*)W)[i];
    for (int i = tid; i < 1024; i += 256) {
        int r = i >> 4, k4 = i & 15;
        int row = rowBase + r;
        float4 v = make_float4(0.f,0.f,0.f,0.f);
        if (row < N) {
            v = ((const float4*)X)[(size_t)row * 16 + k4];
            float nv = norm[row];
            v.x *= nv; v.y *= nv; v.z *= nv; v.w *= nv;
        }
        *((float4*)&Xs[r * XS_STRIDE + (k4 << 2)]) = v;
    }
    __syncthreads();
    int tc = tid & 15, tr = tid >> 4;
    int c0 = tc * 4, r0 = tr * 4;
    float acc[4][4] = {};
#pragma unroll 2
    for (int k = 0; k < 64; k += 4) {
        float4 wv[4];
#pragma unroll
        for (int kk = 0; kk < 4; kk++)
            wv[kk] = *((const float4*)&Ws[(k + kk) * 64 + c0]);
#pragma unroll
        for (int j = 0; j < 4; j++) {
            float4 xv = *((const float4*)&Xs[(r0 + j) * XS_STRIDE + k]);
            acc[j][0] += xv.x * wv[0].x; acc[j][1] += xv.x * wv[0].y;
            acc[j][2] += xv.x * wv[0].z; acc[j][3] += xv.x * wv[0].w;
            acc[j][0] += xv.y * wv[1].x; acc[j][1] += xv.y * wv[1].y;
            acc[j][2] += xv.y * wv[1].z; acc[j][3] += xv.y * wv[1].w;
            acc[j][0] += xv.z * wv[2].x; acc[j][1] += xv.z * wv[2].y;
            acc[j][2] += xv.z * wv[2].z; acc[j][3] += xv.z * wv[2].w;
            acc[j][0] += xv.w * wv[3].x; acc[j][1] += xv.w * wv[3].y;
            acc[j][2] += xv.w * wv[3].z; acc[j][3] += xv.w * wv[3].w;
        }
    }
#pragma unroll
    for (int j = 0; j < 4; j++) {
        int row = rowBase + r0 + j;
        if (row < N) {
            __half2 h01 = __floats2half2_rn(acc[j][0], acc[j][1]);
            __half2 h23 = __floats2half2_rn(acc[j][2], acc[j][3]);
            uint2 pk;
            pk.x = *(unsigned int*)&h01;
            pk.y = *(unsigned int*)&h23;
            *((uint2*)(H + (size_t)row * 64 + c0)) = pk;
        }
    }
}

template<int FC>
__global__ __launch_bounds__(256, 4)
void k_agg_gemm(const uint4* __restrict__ H4, const int* __restrict__ rp,
                const int* __restrict__ bsum, const int* __restrict__ deg,
                const int* __restrict__ col, const float* __restrict__ nd,
                const float* __restrict__ nsrc, const float* __restrict__ bias,
                const float* __restrict__ W, const float* __restrict__ Wb2,
                void* __restrict__ OutP, int N) {
    __shared__ float Xs[64 * XS_STRIDE];
    __shared__ float Ws[FC ? 640 : 4096];
    __shared__ float Wb[16];
    int tid = threadIdx.x;
    if constexpr (FC == 0) {
        for (int i = tid; i < 1024; i += 256)
            ((float4*)Ws)[i] = ((const float4*)W)[i];
    } else {
        for (int i = tid; i < 640; i += 256) {
            int k = i / 10, c = i - k * 10;
            Ws[c * 64 + k] = W[i];
        }
        if (tid < 10) Wb[tid] = Wb2[tid];
    }
    int wave = tid >> 6;
    int lane = tid & 63;
    int g = lane >> 3;
    int l = lane & 7;
    int rowBase = blockIdx.x * 64;
    float4 bv0 = *((const float4*)&bias[l * 8]);
    float4 bv1 = *((const float4*)&bias[l * 8 + 4]);
    int nodeA = rowBase + wave * 16 + g;
    int nodeB = nodeA + 8;
    int stA = 0, nA = 0; float nvA = 0.f, nsA = 0.f;
    if (nodeA < N) {
        stA = rp[nodeA] + bsum[nodeA >> 8];
        nA = deg[nodeA]; nvA = nd[nodeA];
        if constexpr (FC == 0) nsA = nsrc[nodeA];
    }
    int stB = 0, nB = 0; float nvB = 0.f, nsB = 0.f;
    if (nodeB < N) {
        stB = rp[nodeB] + bsum[nodeB >> 8];
        nB = deg[nodeB]; nvB = nd[nodeB];
        if constexpr (FC == 0) nsB = nsrc[nodeB];
    }
    int idxA = (l < nA) ? col[stA + l] : 0;
    int idxB = (l < nB) ? col[stB + l] : 0;
    int mA = nA, mB = nB;
#pragma unroll
    for (int d = 8; d <= 32; d <<= 1) {
        int tA = __shfl_xor(mA, d); mA = mA > tA ? mA : tA;
        int tB = __shfl_xor(mB, d); mB = mB > tB ? mB : tB;
    }
    auto run = [&](int start, int n, int m, int idx, float nv, float nsv,
                   bool vn, int row) {
        float acc[8] = {0.f,0.f,0.f,0.f,0.f,0.f,0.f,0.f};
        for (int j0 = 0; j0 < m; j0 += 8) {
            int idxn = ((j0 + 8 + l) < n) ? col[start + j0 + 8 + l] : 0;
#pragma unroll
            for (int jj = 0; jj < 8; jj++) {
                int s = __shfl(idx, (g << 3) + jj);
                if (j0 + jj < n) {
                    uint4 v = H4[(size_t)s * 8 + l];
                    float2 f0 = __half22float2(*(__half2*)&v.x);
                    float2 f1 = __half22float2(*(__half2*)&v.y);
                    float2 f2 = __half22float2(*(__half2*)&v.z);
                    float2 f3 = __half22float2(*(__half2*)&v.w);
                    acc[0] += f0.x; acc[1] += f0.y; acc[2] += f1.x; acc[3] += f1.y;
                    acc[4] += f2.x; acc[5] += f2.y; acc[6] += f3.x; acc[7] += f3.y;
                }
            }
            idx = idxn;
        }
        float4 o0, o1;
        o0.x = tanhf(acc[0] * nv + bv0.x);
        o0.y = tanhf(acc[1] * nv + bv0.y);
        o0.z = tanhf(acc[2] * nv + bv0.z);
        o0.w = tanhf(acc[3] * nv + bv0.w);
        o1.x = tanhf(acc[4] * nv + bv1.x);
        o1.y = tanhf(acc[5] * nv + bv1.y);
        o1.z = tanhf(acc[6] * nv + bv1.z);
        o1.w = tanhf(acc[7] * nv + bv1.w);
        if constexpr (FC == 0) {
            o0.x *= nsv; o0.y *= nsv; o0.z *= nsv; o0.w *= nsv;
            o1.x *= nsv; o1.y *= nsv; o1.z *= nsv; o1.w *= nsv;
        }
        if (!vn) {
            o0 = make_float4(0.f,0.f,0.f,0.f);
            o1 = make_float4(0.f,0.f,0.f,0.f);
        }
        *((float4*)&Xs[row * XS_STRIDE + l * 8])     = o0;
        *((float4*)&Xs[row * XS_STRIDE + l * 8 + 4]) = o1;
    };
    run(stA, nA, mA, idxA, nvA, nsA, nodeA < N, wave * 16 + g);
    run(stB, nB, mB, idxB, nvB, nsB, nodeB < N, wave * 16 + 8 + g);
    __syncthreads();
    if constexpr (FC == 0) {
        __half* Hh = (__half*)OutP;
        int tc = tid & 15, tr = tid >> 4;
        int c0 = tc * 4, r0 = tr * 4;
        float acc[4][4] = {};
#pragma unroll 2
        for (int k = 0; k < 64; k += 4) {
            float4 wv[4];
#pragma unroll
            for (int kk = 0; kk < 4; kk++)
                wv[kk] = *((const float4*)&Ws[(k + kk) * 64 + c0]);
#pragma unroll
            for (int j = 0; j < 4; j++) {
                float4 xv = *((const float4*)&Xs[(r0 + j) * XS_STRIDE + k]);
                acc[j][0] += xv.x * wv[0].x; acc[j][1] += xv.x * wv[0].y;
                acc[j][2] += xv.x * wv[0].z; acc[j][3] += xv.x * wv[0].w;
                acc[j][0] += xv.y * wv[1].x; acc[j][1] += xv.y * wv[1].y;
                acc[j][2] += xv.y * wv[1].z; acc[j][3] += xv.y * wv[1].w;
                acc[j][0] += xv.z * wv[2].x; acc[j][1] += xv.z * wv[2].y;
                acc[j][2] += xv.z * wv[2].z; acc[j][3] += xv.z * wv[2].w;
                acc[j][0] += xv.w * wv[3].x; acc[j][1] += xv.w * wv[3].y;
                acc[j][2] += xv.w * wv[3].z; acc[j][3] += xv.w * wv[3].w;
            }
        }
#pragma unroll
        for (int j = 0; j < 4; j++) {
            int row = rowBase + r0 + j;
            if (row < N) {
                __half2 h01 = __floats2half2_rn(acc[j][0], acc[j][1]);
                __half2 h23 = __floats2half2_rn(acc[j][2], acc[j][3]);
                uint2 pk;
                pk.x = *(unsigned int*)&h01;
                pk.y = *(unsigned int*)&h23;
                *((uint2*)(Hh + (size_t)row * 64 + c0)) = pk;
            }
        }
    } else {
        float* outF = (float*)OutP;
        for (int idx = tid; idx < 640; idx += 256) {
            int ln = idx / 10;
            int cl = idx - ln * 10;
            float acc = Wb[cl];
#pragma unroll
            for (int k = 0; k < 64; k += 4) {
                float4 xv = *((const float4*)&Xs[ln * XS_STRIDE + k]);
                float4 wv = *((const float4*)&Ws[cl * 64 + k]);
                acc += xv.x * wv.x + xv.y * wv.y + xv.z * wv.z + xv.w * wv.w;
            }
            int row = rowBase + ln;
            if (row < N) outF[(size_t)row * 10 + cl] = acc;
        }
    }
}

// ===================== launcher =====================
extern "C" void kernel_launch(void* const* d_in, const int* in_sizes, int n_in,
                              void* d_out, int out_size, void* d_ws, size_t ws_size,
                              hipStream_t stream) {
    const float* x   = (const float*)d_in[0];
    const int*   src = (const int*)d_in[1];
    const int*   dst = (const int*)d_in[2];
    const float* W1  = (const float*)d_in[3];
    const float* b1  = (const float*)d_in[4];
    const float* W2  = (const float*)d_in[5];
    const float* b2  = (const float*)d_in[6];
    const float* W3  = (const float*)d_in[7];
    const float* b3  = (const float*)d_in[8];
    const float* Wfc = (const float*)d_in[9];
    const float* bfc = (const float*)d_in[10];
    float* out = (float*)d_out;
    int N = in_sizes[0] / 64;
    int E = in_sizes[1];
    int P = (E + CHUNK - 1) >> CHUNK_SHIFT;
    int words = (N + 3) / 4;

    char* ws = (char*)d_ws;
    size_t p = 0;
    auto alloc = [&](size_t bytes) -> void* {
        void* r = ws + p;
        p = (p + bytes + 255) & ~(size_t)255;
        return r;
    };
    int*    deg_s = (int*)alloc((size_t)N * 4);
    int*    deg_d = (int*)alloc((size_t)N * 4);
    int*    rowStart = (int*)alloc((size_t)N * 4);
    int*    cur   = (int*)alloc((size_t)N * 4);
    float*  ns    = (float*)alloc((size_t)N * 4);
    float*  nd    = (float*)alloc((size_t)N * 4);
    int*    col   = (int*)alloc((size_t)E * 4);
    __half* bufH  = (__half*)alloc((size_t)N * 64 * 2);
    __half* bufH2 = (__half*)alloc((size_t)N * 64 * 2);
    unsigned int* counter = (unsigned int*)alloc(256);
    // fallback-only arrays
    int*    rp    = (int*)alloc((size_t)N * 4);
    int*    bsum  = (int*)alloc((size_t)THREADS * 4);
    unsigned char* rank = (unsigned char*)alloc((size_t)E);
    unsigned int* partS = (unsigned int*)alloc((size_t)P * words * 4);
    unsigned int* partD = (unsigned int*)alloc((size_t)P * words * 4);
    unsigned int* prefD = (unsigned int*)alloc((size_t)P * words * 4);
    (void)ws_size; (void)n_in; (void)out_size;

    // cooperative capacity (cached; any grid size is correct — all phases grid-stride)
    static int coopGrid = -2;
    if (coopGrid == -2) {
        int bpc = 0;
        if (hipOccupancyMaxActiveBlocksPerMultiprocessor(&bpc, k_all, 256, 0)
                == hipSuccess && bpc > 0) {
            coopGrid = bpc * 256;           // 256 CUs on MI355X
            if (coopGrid > 2048) coopGrid = 2048;
        } else {
            coopGrid = 0;
        }
    }

    bool launched = false;
    if (coopGrid > 0) {
        GP gp;
        gp.x = x; gp.src = src; gp.dst = dst;
        gp.W1 = W1; gp.b1 = b1; gp.W2 = W2; gp.b2 = b2;
        gp.W3 = W3; gp.b3 = b3; gp.Wfc = Wfc; gp.bfc = bfc;
        gp.out = out;
        gp.deg_s = deg_s; gp.deg_d = deg_d; gp.rowStart = rowStart; gp.cur = cur;
        gp.ns = ns; gp.nd = nd; gp.col = col;
        gp.bufH = bufH; gp.bufH2 = bufH2; gp.counter = counter;
        gp.N = N; gp.E = E;
        void* args[] = { &gp };
        if (hipLaunchCooperativeKernel(k_all, dim3(coopGrid), dim3(256),
                                       args, 0, stream) == hipSuccess)
            launched = true;
        else
            coopGrid = 0;   // don't retry every call
    }

    if (!launched) {
        int gFill = (E + 255) / 256;
        int gP = (words + 63) / 64;
        int gG = (N + 63) / 64;
        k_hist<<<2 * P, 1024, 0, stream>>>(src, dst, partS, partD, rank, counter, E, P, words);
        k_pre <<<gP, THREADS, 0, stream>>>(partS, partD, prefD, deg_d, ns, nd,
                                           rp, bsum, counter, P, words, N);
        k_fill_gemm<<<gFill + gG, 256, 0, stream>>>(src, dst, rp, bsum, rank, prefD,
                                                    col, E, words, gFill,
                                                    x, ns, W1, bufH, N);
        k_agg_gemm<0><<<gG, 256, 0, stream>>>((const uint4*)bufH,  rp, bsum, deg_d, col,
                                              nd, ns, b1, W2, nullptr, bufH2, N);
        k_agg_gemm<0><<<gG, 256, 0, stream>>>((const uint4*)bufH2, rp, bsum, deg_d, col,
                                              nd, ns, b2, W3, nullptr, bufH, N);
        k_agg_gemm<1><<<gG, 256, 0, stream>>>((const uint4*)bufH,  rp, bsum, deg_d, col,
                                              nd, ns, b3, Wfc, bfc, out, N);
    }
}

// Round 5
// 266.528 us; speedup vs baseline: 3.5894x; 3.5894x over previous
//
#include <hip/hip_runtime.h>
#include <hip/hip_fp16.h>
#include <math.h>

#define THREADS 256
#define CHUNK_SHIFT 15
#define CHUNK (1 << CHUNK_SHIFT)
#define LDS_WORDS 12500   // ceil(N/4) for N=50000, 8-bit packed counters
#define MAXB 16           // max chunks per quarter in k_pre (holds for P <= 64)
#define XS_STRIDE 68

// H layout (both bufH and bufH2): split channel halves for L2 residency.
//   Hlo = base            : N rows x 32 ch (3.2 MB, contiguous)
//   Hhi = base + N*32     : N rows x 32 ch (3.2 MB, contiguous)
// Each agg pass gathers from ONE 3.2 MB half -> fits a 4 MB per-XCD L2.

// ---- privatized LDS histogram, 4 bins/word (8-bit); dst blocks capture rank ----
__global__ __launch_bounds__(1024)
void k_hist(const int* __restrict__ src, const int* __restrict__ dst,
            unsigned int* __restrict__ partS, unsigned int* __restrict__ partD,
            unsigned char* __restrict__ rank, unsigned int* __restrict__ counter,
            int E, int P, int words) {
    __shared__ unsigned int hist[LDS_WORDS];
    if (blockIdx.x == 0 && threadIdx.x == 0) *counter = 0u;
    int isSrc = (blockIdx.x >= (unsigned)P);
    int b = isSrc ? (blockIdx.x - P) : blockIdx.x;
    int tid = threadIdx.x;

    for (int w = tid; w < words; w += 1024) hist[w] = 0u;
    __syncthreads();

    int start = b << CHUNK_SHIFT;
    int end = start + CHUNK; if (end > E) end = E;

    if (isSrc) {
        for (int e = start + tid; e < end; e += 1024) {
            int s = src[e];
            atomicAdd(&hist[s >> 2], 1u << ((s & 3) * 8));
        }
    } else {
        for (int e = start + tid; e < end; e += 1024) {
            int d = dst[e];
            unsigned int old = atomicAdd(&hist[d >> 2], 1u << ((d & 3) * 8));
            rank[e] = (unsigned char)((old >> ((d & 3) * 8)) & 0xFFu);
        }
    }
    __syncthreads();

    unsigned int* part = isSrc ? partS : partD;
    for (int w = tid; w < words; w += 1024)
        part[(size_t)b * words + w] = hist[w];
}

// ---- k_pre: one packed word (4 nodes) per thread, chunk range split 4-way ----
__global__ __launch_bounds__(THREADS)
void k_pre(const unsigned int* __restrict__ partS,
           const unsigned int* __restrict__ partD,
           unsigned int* __restrict__ prefD,
           int* __restrict__ deg_d, float* __restrict__ ns, float* __restrict__ nd,
           int* __restrict__ rp, int* __restrict__ bsum,
           unsigned int* __restrict__ counter,
           int P, int words, int N) {
    __shared__ unsigned int qsD[4][64];
    __shared__ unsigned int qsS[4][64];
    int t = threadIdx.x;
    int widx = t & 63;
    int q = t >> 6;
    int w = blockIdx.x * 64 + widx;
    bool valid = (w < words);

    int per = (P + 3) >> 2;
    int blo = q * per;
    int cnt = P - blo; if (cnt > per) cnt = per; if (cnt < 0) cnt = 0;

    unsigned int vD[MAXB];
    unsigned int runD = 0, runS = 0;
#pragma unroll
    for (int bb = 0; bb < MAXB; bb++) {
        unsigned int vd = 0, vs = 0;
        if (bb < cnt && valid) {
            size_t off = (size_t)(blo + bb) * words + w;
            vd = partD[off];
            vs = partS[off];
        }
        vD[bb] = vd;
        runD += vd;
        runS += vs;
    }
    qsD[q][widx] = runD;
    qsS[q][widx] = runS;
    __syncthreads();

    unsigned int baseD = 0, totD = 0, totS = 0;
#pragma unroll
    for (int qq = 0; qq < 4; qq++) {
        unsigned int xd = qsD[qq][widx];
        unsigned int xs = qsS[qq][widx];
        if (qq < q) baseD += xd;
        totD += xd;
        totS += xs;
    }

    unsigned int pref = baseD;
#pragma unroll
    for (int bb = 0; bb < MAXB; bb++) {
        if (bb < cnt && valid)
            prefD[(size_t)(blo + bb) * words + w] = pref;
        pref += vD[bb];
    }

    if (q == 0) {
        int b0 = (int)(totD & 0xFFu), b1 = (int)((totD >> 8) & 0xFFu),
            b2 = (int)((totD >> 16) & 0xFFu), b3 = (int)((totD >> 24) & 0xFFu);
        int wsum = b0 + b1 + b2 + b3;
        int incl = wsum;
#pragma unroll
        for (int off = 1; off < 64; off <<= 1) {
            int y = __shfl_up(incl, off);
            if (widx >= off) incl += y;
        }
        int excl = incl - wsum;
        int btot = __shfl(incl, 63);
        if (widx == 0)
            bsum[blockIdx.x] = (int)atomicAdd(counter, (unsigned int)btot);
        if (valid) {
            int s0 = (int)(totS & 0xFFu), s1 = (int)((totS >> 8) & 0xFFu),
                s2 = (int)((totS >> 16) & 0xFFu), s3 = (int)((totS >> 24) & 0xFFu);
            int4 dv; dv.x = b0; dv.y = b1; dv.z = b2; dv.w = b3;
            *(int4*)&deg_d[(size_t)4 * w] = dv;
            float4 ndv;
            ndv.x = b0 ? 1.0f / sqrtf((float)b0) : 0.0f;
            ndv.y = b1 ? 1.0f / sqrtf((float)b1) : 0.0f;
            ndv.z = b2 ? 1.0f / sqrtf((float)b2) : 0.0f;
            ndv.w = b3 ? 1.0f / sqrtf((float)b3) : 0.0f;
            *(float4*)&nd[(size_t)4 * w] = ndv;
            float4 nsv;
            nsv.x = s0 ? 1.0f / sqrtf((float)s0) : 0.0f;
            nsv.y = s1 ? 1.0f / sqrtf((float)s1) : 0.0f;
            nsv.z = s2 ? 1.0f / sqrtf((float)s2) : 0.0f;
            nsv.w = s3 ? 1.0f / sqrtf((float)s3) : 0.0f;
            *(float4*)&ns[(size_t)4 * w] = nsv;
            int4 rv; rv.x = excl; rv.y = excl + b0;
            rv.z = excl + b0 + b1; rv.w = excl + b0 + b1 + b2;
            *(int4*)&rp[(size_t)4 * w] = rv;
        }
    }
}

// ---- merged: CSR fill (blocks [0,gFill)) || layer-1 GEMM (blocks [gFill, ...)) ----
__global__ __launch_bounds__(256, 4)
void k_fill_gemm(const int* __restrict__ src, const int* __restrict__ dst,
                 const int* __restrict__ rp, const int* __restrict__ bsum,
                 const unsigned char* __restrict__ rank,
                 const unsigned int* __restrict__ prefD,
                 int* __restrict__ col, int E, int words, int gFill,
                 const float* __restrict__ X, const float* __restrict__ norm,
                 const float* __restrict__ W, __half* __restrict__ H, int N) {
    __shared__ float Xs[64 * XS_STRIDE];
    __shared__ float Ws[64 * 64];
    int tid = threadIdx.x;

    if ((int)blockIdx.x < gFill) {
        int e = blockIdx.x * 256 + tid;
        if (e < E) {
            int d = dst[e];
            int b = e >> CHUNK_SHIFT;
            unsigned int pk = prefD[(size_t)b * words + (d >> 2)];
            int pref = (int)((pk >> ((d & 3) * 8)) & 0xFFu);
            col[rp[d] + bsum[d >> 8] + pref + (int)rank[e]] = src[e];
        }
        return;
    }

    int rowBase = ((int)blockIdx.x - gFill) * 64;
    for (int i = tid; i < 1024; i += 256)
        ((float4*)Ws)[i] = ((const float4*)W)[i];
    for (int i = tid; i < 1024; i += 256) {
        int r = i >> 4, k4 = i & 15;
        int row = rowBase + r;
        float4 v = make_float4(0.f, 0.f, 0.f, 0.f);
        if (row < N) {
            v = ((const float4*)X)[(size_t)row * 16 + k4];
            float nv = norm[row];
            v.x *= nv; v.y *= nv; v.z *= nv; v.w *= nv;
        }
        *((float4*)&Xs[r * XS_STRIDE + (k4 << 2)]) = v;
    }
    __syncthreads();

    int tc = tid & 15, tr = tid >> 4;
    int c0 = tc * 4, r0 = tr * 4;
    float acc[4][4] = {};

#pragma unroll 2
    for (int k = 0; k < 64; k += 4) {
        float4 wv[4];
#pragma unroll
        for (int kk = 0; kk < 4; kk++)
            wv[kk] = *((const float4*)&Ws[(k + kk) * 64 + c0]);
#pragma unroll
        for (int j = 0; j < 4; j++) {
            float4 xv = *((const float4*)&Xs[(r0 + j) * XS_STRIDE + k]);
            acc[j][0] += xv.x * wv[0].x; acc[j][1] += xv.x * wv[0].y;
            acc[j][2] += xv.x * wv[0].z; acc[j][3] += xv.x * wv[0].w;
            acc[j][0] += xv.y * wv[1].x; acc[j][1] += xv.y * wv[1].y;
            acc[j][2] += xv.y * wv[1].z; acc[j][3] += xv.y * wv[1].w;
            acc[j][0] += xv.z * wv[2].x; acc[j][1] += xv.z * wv[2].y;
            acc[j][2] += xv.z * wv[2].z; acc[j][3] += xv.z * wv[2].w;
            acc[j][0] += xv.w * wv[3].x; acc[j][1] += xv.w * wv[3].y;
            acc[j][2] += xv.w * wv[3].z; acc[j][3] += xv.w * wv[3].w;
        }
    }
    // split-half store: channels [c0,c0+4) -> Hlo (tc<8) or Hhi (tc>=8)
    __half* Hh = H + (tc >= 8 ? (size_t)N * 32 : (size_t)0);
    int cc = c0 & 31;
#pragma unroll
    for (int j = 0; j < 4; j++) {
        int row = rowBase + r0 + j;
        if (row < N) {
            __half2 h01 = __floats2half2_rn(acc[j][0], acc[j][1]);
            __half2 h23 = __floats2half2_rn(acc[j][2], acc[j][3]);
            uint2 pk;
            pk.x = *(unsigned int*)&h01;
            pk.y = *(unsigned int*)&h23;
            *((uint2*)(Hh + (size_t)row * 32 + cc)) = pk;
        }
    }
}

// ---- fused agg + next-layer GEMM (FC=0) or agg + final FC (FC=1) ----
// Phase A: TWO passes over the edge list, one per 3.2 MB channel-half of H
// (each half fits a 4 MB per-XCD L2). 8 nodes in flight per wave per round;
// lane l = lane&7 owns 4 channels of the current half (uint2 gather, 64B/row).
// col is read nontemporally so streaming it doesn't evict the gather set.
// Per-channel edge summation order is identical to the single-pass version.
template<int FC>
__global__ __launch_bounds__(256, 4)
void k_agg_gemm(const __half* __restrict__ Hbase, const int* __restrict__ rp,
                const int* __restrict__ bsum, const int* __restrict__ deg,
                const int* __restrict__ col, const float* __restrict__ nd,
                const float* __restrict__ nsrc, const float* __restrict__ bias,
                const float* __restrict__ W, const float* __restrict__ Wb2,
                void* __restrict__ OutP, int N) {
    __shared__ float Xs[64 * XS_STRIDE];
    __shared__ float Ws[FC ? 640 : 4096];
    __shared__ float Wb[16];
    int tid = threadIdx.x;

    if constexpr (FC == 0) {
        for (int i = tid; i < 1024; i += 256)
            ((float4*)Ws)[i] = ((const float4*)W)[i];
    } else {
        for (int i = tid; i < 640; i += 256) {   // Ws[c*64+k] = Wfc[k][c]
            int k = i / 10, c = i - k * 10;
            Ws[c * 64 + k] = W[i];
        }
        if (tid < 10) Wb[tid] = Wb2[tid];
    }

    int wave = tid >> 6;
    int lane = tid & 63;
    int g = lane >> 3;   // node sub-index within a round (8 groups)
    int l = lane & 7;    // uint2 slot: 4 channels of the current half
    int rowBase = blockIdx.x * 64;

    int nodeA = rowBase + wave * 16 + g;
    int nodeB = nodeA + 8;

    int stA = 0, nA = 0; float nvA = 0.f, nsA = 0.f;
    if (nodeA < N) {
        stA = rp[nodeA] + bsum[nodeA >> 8];
        nA  = deg[nodeA];
        nvA = nd[nodeA];
        if constexpr (FC == 0) nsA = nsrc[nodeA];
    }
    int stB = 0, nB = 0; float nvB = 0.f, nsB = 0.f;
    if (nodeB < N) {
        stB = rp[nodeB] + bsum[nodeB >> 8];
        nB  = deg[nodeB];
        nvB = nd[nodeB];
        if constexpr (FC == 0) nsB = nsrc[nodeB];
    }

    // wave-uniform loop bounds (max deg across the 8 groups), reused both passes
    int mA = nA, mB = nB;
#pragma unroll
    for (int d = 8; d <= 32; d <<= 1) {
        int tA = __shfl_xor(mA, d); mA = mA > tA ? mA : tA;
        int tB = __shfl_xor(mB, d); mB = mB > tB ? mB : tB;
    }

    // bias fragments per pass: channels pass*32 + l*4 .. +4
    float4 bvp0 = *((const float4*)&bias[l * 4]);
    float4 bvp1 = *((const float4*)&bias[32 + l * 4]);

    auto run = [&](const uint2* __restrict__ H2, float4 bv, int xb,
                   int start, int n, int m, float nv, float nsv,
                   bool vn, int row) {
        int idx = (l < n) ? __builtin_nontemporal_load(&col[start + l]) : 0;
        float acc[4] = {0.f, 0.f, 0.f, 0.f};
        for (int j0 = 0; j0 < m; j0 += 8) {
            int idxn = ((j0 + 8 + l) < n)
                     ? __builtin_nontemporal_load(&col[start + j0 + 8 + l]) : 0;
#pragma unroll
            for (int jj = 0; jj < 8; jj++) {
                int s = __shfl(idx, (g << 3) + jj);
                if (j0 + jj < n) {
                    uint2 v = H2[(size_t)s * 8 + l];
                    float2 f0 = __half22float2(*(__half2*)&v.x);
                    float2 f1 = __half22float2(*(__half2*)&v.y);
                    acc[0] += f0.x; acc[1] += f0.y;
                    acc[2] += f1.x; acc[3] += f1.y;
                }
            }
            idx = idxn;
        }
        float4 o;
        o.x = tanhf(acc[0] * nv + bv.x);
        o.y = tanhf(acc[1] * nv + bv.y);
        o.z = tanhf(acc[2] * nv + bv.z);
        o.w = tanhf(acc[3] * nv + bv.w);
        if constexpr (FC == 0) {
            o.x *= nsv; o.y *= nsv; o.z *= nsv; o.w *= nsv;
        }
        if (!vn) o = make_float4(0.f, 0.f, 0.f, 0.f);
        *((float4*)&Xs[row * XS_STRIDE + xb + l * 4]) = o;
    };

    {   // pass 0: channels 0..31 from Hlo
        const uint2* H2 = (const uint2*)Hbase;
        run(H2, bvp0, 0,  stA, nA, mA, nvA, nsA, nodeA < N, wave * 16 + g);
        run(H2, bvp0, 0,  stB, nB, mB, nvB, nsB, nodeB < N, wave * 16 + 8 + g);
    }
    {   // pass 1: channels 32..63 from Hhi
        const uint2* H2 = (const uint2*)(Hbase + (size_t)N * 32);
        run(H2, bvp1, 32, stA, nA, mA, nvA, nsA, nodeA < N, wave * 16 + g);
        run(H2, bvp1, 32, stB, nB, mB, nvB, nsB, nodeB < N, wave * 16 + 8 + g);
    }
    __syncthreads();

    // ---- phase B
    if constexpr (FC == 0) {
        __half* Hout = (__half*)OutP;
        int tc = tid & 15, tr = tid >> 4;
        int c0 = tc * 4, r0 = tr * 4;
        float acc[4][4] = {};

#pragma unroll 2
        for (int k = 0; k < 64; k += 4) {
            float4 wv[4];
#pragma unroll
            for (int kk = 0; kk < 4; kk++)
                wv[kk] = *((const float4*)&Ws[(k + kk) * 64 + c0]);
#pragma unroll
            for (int j = 0; j < 4; j++) {
                float4 xv = *((const float4*)&Xs[(r0 + j) * XS_STRIDE + k]);
                acc[j][0] += xv.x * wv[0].x; acc[j][1] += xv.x * wv[0].y;
                acc[j][2] += xv.x * wv[0].z; acc[j][3] += xv.x * wv[0].w;
                acc[j][0] += xv.y * wv[1].x; acc[j][1] += xv.y * wv[1].y;
                acc[j][2] += xv.y * wv[1].z; acc[j][3] += xv.y * wv[1].w;
                acc[j][0] += xv.z * wv[2].x; acc[j][1] += xv.z * wv[2].y;
                acc[j][2] += xv.z * wv[2].z; acc[j][3] += xv.z * wv[2].w;
                acc[j][0] += xv.w * wv[3].x; acc[j][1] += xv.w * wv[3].y;
                acc[j][2] += xv.w * wv[3].z; acc[j][3] += xv.w * wv[3].w;
            }
        }
        __half* Hh = Hout + (tc >= 8 ? (size_t)N * 32 : (size_t)0);
        int cc = c0 & 31;
#pragma unroll
        for (int j = 0; j < 4; j++) {
            int row = rowBase + r0 + j;
            if (row < N) {
                __half2 h01 = __floats2half2_rn(acc[j][0], acc[j][1]);
                __half2 h23 = __floats2half2_rn(acc[j][2], acc[j][3]);
                uint2 pk;
                pk.x = *(unsigned int*)&h01;
                pk.y = *(unsigned int*)&h23;
                *((uint2*)(Hh + (size_t)row * 32 + cc)) = pk;
            }
        }
    } else {
        float* outF = (float*)OutP;
        for (int idx = tid; idx < 640; idx += 256) {
            int ln = idx / 10;
            int cl = idx - ln * 10;
            float acc = Wb[cl];
#pragma unroll
            for (int k = 0; k < 64; k += 4) {
                float4 xv = *((const float4*)&Xs[ln * XS_STRIDE + k]);
                float4 wv = *((const float4*)&Ws[cl * 64 + k]);
                acc += xv.x * wv.x + xv.y * wv.y + xv.z * wv.z + xv.w * wv.w;
            }
            int row = rowBase + ln;
            if (row < N) outF[(size_t)row * 10 + cl] = acc;
        }
    }
}

extern "C" void kernel_launch(void* const* d_in, const int* in_sizes, int n_in,
                              void* d_out, int out_size, void* d_ws, size_t ws_size,
                              hipStream_t stream) {
    const float* x   = (const float*)d_in[0];
    const int*   src = (const int*)d_in[1];
    const int*   dst = (const int*)d_in[2];
    const float* W1  = (const float*)d_in[3];
    const float* b1  = (const float*)d_in[4];
    const float* W2  = (const float*)d_in[5];
    const float* b2  = (const float*)d_in[6];
    const float* W3  = (const float*)d_in[7];
    const float* b3  = (const float*)d_in[8];
    const float* Wfc = (const float*)d_in[9];
    const float* bfc = (const float*)d_in[10];
    float* out = (float*)d_out;
    int N = in_sizes[0] / 64;
    int E = in_sizes[1];
    int P = (E + CHUNK - 1) >> CHUNK_SHIFT;
    int words = (N + 3) / 4;

    char* ws = (char*)d_ws;
    size_t p = 0;
    auto alloc = [&](size_t bytes) -> void* {
        void* r = ws + p;
        p = (p + bytes + 255) & ~(size_t)255;
        return r;
    };
    int*    deg_d = (int*)alloc((size_t)N * 4);
    int*    rp    = (int*)alloc((size_t)N * 4);
    int*    bsum  = (int*)alloc((size_t)THREADS * 4);
    unsigned char* rank = (unsigned char*)alloc((size_t)E);
    int*    col   = (int*)alloc((size_t)E * 4);
    float*  ns    = (float*)alloc((size_t)N * 4);
    float*  nd    = (float*)alloc((size_t)N * 4);
    unsigned int* partS = (unsigned int*)alloc((size_t)P * words * 4);
    unsigned int* partD = (unsigned int*)alloc((size_t)P * words * 4);
    unsigned int* prefD = (unsigned int*)alloc((size_t)P * words * 4);
    __half* bufH  = (__half*)alloc((size_t)N * 64 * 2);
    __half* bufH2 = (__half*)alloc((size_t)N * 64 * 2);
    unsigned int* counter = (unsigned int*)alloc(4);
    (void)ws_size; (void)n_in; (void)out_size;

    int gFill = (E + 255) / 256;
    int gP = (words + 63) / 64;
    int gG = (N + 63) / 64;

    k_hist<<<2 * P, 1024, 0, stream>>>(src, dst, partS, partD, rank, counter, E, P, words);
    k_pre <<<gP, THREADS, 0, stream>>>(partS, partD, prefD, deg_d, ns, nd,
                                       rp, bsum, counter, P, words, N);
    k_fill_gemm<<<gFill + gG, 256, 0, stream>>>(src, dst, rp, bsum, rank, prefD,
                                                col, E, words, gFill,
                                                x, ns, W1, bufH, N);
    k_agg_gemm<0><<<gG, 256, 0, stream>>>(bufH,  rp, bsum, deg_d, col,
                                          nd, ns, b1, W2, nullptr, bufH2, N);
    k_agg_gemm<0><<<gG, 256, 0, stream>>>(bufH2, rp, bsum, deg_d, col,
                                          nd, ns, b2, W3, nullptr, bufH, N);
    k_agg_gemm<1><<<gG, 256, 0, stream>>>(bufH,  rp, bsum, deg_d, col,
                                          nd, ns, b3, Wfc, bfc, out, N);
}

// Round 6
// 199.884 us; speedup vs baseline: 4.7862x; 1.3334x over previous
//
#include <hip/hip_runtime.h>
#include <hip/hip_fp16.h>
#include <math.h>

#define THREADS 256
#define CHUNK_SHIFT 15
#define CHUNK (1 << CHUNK_SHIFT)
#define LDS_WORDS 12500   // ceil(N/4) for N=50000, 8-bit packed counters
#define MAXB 16           // max chunks per quarter in k_pre (holds for P <= 64)
#define XS_STRIDE 68

// ---- privatized LDS histogram, 4 bins/word (8-bit); dst blocks capture rank ----
__global__ __launch_bounds__(1024)
void k_hist(const int* __restrict__ src, const int* __restrict__ dst,
            unsigned int* __restrict__ partS, unsigned int* __restrict__ partD,
            unsigned char* __restrict__ rank, unsigned int* __restrict__ counter,
            int E, int P, int words) {
    __shared__ unsigned int hist[LDS_WORDS];
    if (blockIdx.x == 0 && threadIdx.x == 0) *counter = 0u;
    int isSrc = (blockIdx.x >= (unsigned)P);
    int b = isSrc ? (blockIdx.x - P) : blockIdx.x;
    int tid = threadIdx.x;

    for (int w = tid; w < words; w += 1024) hist[w] = 0u;
    __syncthreads();

    int start = b << CHUNK_SHIFT;
    int end = start + CHUNK; if (end > E) end = E;

    if (isSrc) {
        for (int e = start + tid; e < end; e += 1024) {
            int s = src[e];
            atomicAdd(&hist[s >> 2], 1u << ((s & 3) * 8));
        }
    } else {
        for (int e = start + tid; e < end; e += 1024) {
            int d = dst[e];
            unsigned int old = atomicAdd(&hist[d >> 2], 1u << ((d & 3) * 8));
            rank[e] = (unsigned char)((old >> ((d & 3) * 8)) & 0xFFu);
        }
    }
    __syncthreads();

    unsigned int* part = isSrc ? partS : partD;
    for (int w = tid; w < words; w += 1024)
        part[(size_t)b * words + w] = hist[w];
}

// ---- k_pre: one packed word (4 nodes) per thread, chunk range split 4-way ----
__global__ __launch_bounds__(THREADS)
void k_pre(const unsigned int* __restrict__ partS,
           const unsigned int* __restrict__ partD,
           unsigned int* __restrict__ prefD,
           int* __restrict__ deg_d, float* __restrict__ ns, float* __restrict__ nd,
           int* __restrict__ rp, int* __restrict__ bsum,
           unsigned int* __restrict__ counter,
           int P, int words, int N) {
    __shared__ unsigned int qsD[4][64];
    __shared__ unsigned int qsS[4][64];
    int t = threadIdx.x;
    int widx = t & 63;
    int q = t >> 6;
    int w = blockIdx.x * 64 + widx;
    bool valid = (w < words);

    int per = (P + 3) >> 2;
    int blo = q * per;
    int cnt = P - blo; if (cnt > per) cnt = per; if (cnt < 0) cnt = 0;

    unsigned int vD[MAXB];
    unsigned int runD = 0, runS = 0;
#pragma unroll
    for (int bb = 0; bb < MAXB; bb++) {
        unsigned int vd = 0, vs = 0;
        if (bb < cnt && valid) {
            size_t off = (size_t)(blo + bb) * words + w;
            vd = partD[off];
            vs = partS[off];
        }
        vD[bb] = vd;
        runD += vd;
        runS += vs;
    }
    qsD[q][widx] = runD;
    qsS[q][widx] = runS;
    __syncthreads();

    unsigned int baseD = 0, totD = 0, totS = 0;
#pragma unroll
    for (int qq = 0; qq < 4; qq++) {
        unsigned int xd = qsD[qq][widx];
        unsigned int xs = qsS[qq][widx];
        if (qq < q) baseD += xd;
        totD += xd;
        totS += xs;
    }

    unsigned int pref = baseD;
#pragma unroll
    for (int bb = 0; bb < MAXB; bb++) {
        if (bb < cnt && valid)
            prefD[(size_t)(blo + bb) * words + w] = pref;
        pref += vD[bb];
    }

    if (q == 0) {
        int b0 = (int)(totD & 0xFFu), b1 = (int)((totD >> 8) & 0xFFu),
            b2 = (int)((totD >> 16) & 0xFFu), b3 = (int)((totD >> 24) & 0xFFu);
        int wsum = b0 + b1 + b2 + b3;
        int incl = wsum;
#pragma unroll
        for (int off = 1; off < 64; off <<= 1) {
            int y = __shfl_up(incl, off);
            if (widx >= off) incl += y;
        }
        int excl = incl - wsum;
        int btot = __shfl(incl, 63);
        if (widx == 0)
            bsum[blockIdx.x] = (int)atomicAdd(counter, (unsigned int)btot);
        if (valid) {
            int s0 = (int)(totS & 0xFFu), s1 = (int)((totS >> 8) & 0xFFu),
                s2 = (int)((totS >> 16) & 0xFFu), s3 = (int)((totS >> 24) & 0xFFu);
            int4 dv; dv.x = b0; dv.y = b1; dv.z = b2; dv.w = b3;
            *(int4*)&deg_d[(size_t)4 * w] = dv;
            float4 ndv;
            ndv.x = b0 ? 1.0f / sqrtf((float)b0) : 0.0f;
            ndv.y = b1 ? 1.0f / sqrtf((float)b1) : 0.0f;
            ndv.z = b2 ? 1.0f / sqrtf((float)b2) : 0.0f;
            ndv.w = b3 ? 1.0f / sqrtf((float)b3) : 0.0f;
            *(float4*)&nd[(size_t)4 * w] = ndv;
            float4 nsv;
            nsv.x = s0 ? 1.0f / sqrtf((float)s0) : 0.0f;
            nsv.y = s1 ? 1.0f / sqrtf((float)s1) : 0.0f;
            nsv.z = s2 ? 1.0f / sqrtf((float)s2) : 0.0f;
            nsv.w = s3 ? 1.0f / sqrtf((float)s3) : 0.0f;
            *(float4*)&ns[(size_t)4 * w] = nsv;
            int4 rv; rv.x = excl; rv.y = excl + b0;
            rv.z = excl + b0 + b1; rv.w = excl + b0 + b1 + b2;
            *(int4*)&rp[(size_t)4 * w] = rv;
        }
    }
}

// ---- merged: CSR fill (blocks [0,gFill)) || layer-1 GEMM (blocks [gFill, ...)) ----
__global__ __launch_bounds__(256, 4)
void k_fill_gemm(const int* __restrict__ src, const int* __restrict__ dst,
                 const int* __restrict__ rp, const int* __restrict__ bsum,
                 const unsigned char* __restrict__ rank,
                 const unsigned int* __restrict__ prefD,
                 int* __restrict__ col, int E, int words, int gFill,
                 const float* __restrict__ X, const float* __restrict__ norm,
                 const float* __restrict__ W, __half* __restrict__ H, int N) {
    __shared__ float Xs[64 * XS_STRIDE];
    __shared__ float Ws[64 * 64];
    int tid = threadIdx.x;

    if ((int)blockIdx.x < gFill) {
        int e = blockIdx.x * 256 + tid;
        if (e < E) {
            int d = dst[e];
            int b = e >> CHUNK_SHIFT;
            unsigned int pk = prefD[(size_t)b * words + (d >> 2)];
            int pref = (int)((pk >> ((d & 3) * 8)) & 0xFFu);
            col[rp[d] + bsum[d >> 8] + pref + (int)rank[e]] = src[e];
        }
        return;
    }

    int rowBase = ((int)blockIdx.x - gFill) * 64;
    for (int i = tid; i < 1024; i += 256)
        ((float4*)Ws)[i] = ((const float4*)W)[i];
    for (int i = tid; i < 1024; i += 256) {
        int r = i >> 4, k4 = i & 15;
        int row = rowBase + r;
        float4 v = make_float4(0.f, 0.f, 0.f, 0.f);
        if (row < N) {
            v = ((const float4*)X)[(size_t)row * 16 + k4];
            float nv = norm[row];
            v.x *= nv; v.y *= nv; v.z *= nv; v.w *= nv;
        }
        *((float4*)&Xs[r * XS_STRIDE + (k4 << 2)]) = v;
    }
    __syncthreads();

    int tc = tid & 15, tr = tid >> 4;
    int c0 = tc * 4, r0 = tr * 4;
    float acc[4][4] = {};

#pragma unroll 2
    for (int k = 0; k < 64; k += 4) {
        float4 wv[4];
#pragma unroll
        for (int kk = 0; kk < 4; kk++)
            wv[kk] = *((const float4*)&Ws[(k + kk) * 64 + c0]);
#pragma unroll
        for (int j = 0; j < 4; j++) {
            float4 xv = *((const float4*)&Xs[(r0 + j) * XS_STRIDE + k]);
            acc[j][0] += xv.x * wv[0].x; acc[j][1] += xv.x * wv[0].y;
            acc[j][2] += xv.x * wv[0].z; acc[j][3] += xv.x * wv[0].w;
            acc[j][0] += xv.y * wv[1].x; acc[j][1] += xv.y * wv[1].y;
            acc[j][2] += xv.y * wv[1].z; acc[j][3] += xv.y * wv[1].w;
            acc[j][0] += xv.z * wv[2].x; acc[j][1] += xv.z * wv[2].y;
            acc[j][2] += xv.z * wv[2].z; acc[j][3] += xv.z * wv[2].w;
            acc[j][0] += xv.w * wv[3].x; acc[j][1] += xv.w * wv[3].y;
            acc[j][2] += xv.w * wv[3].z; acc[j][3] += xv.w * wv[3].w;
        }
    }
#pragma unroll
    for (int j = 0; j < 4; j++) {
        int row = rowBase + r0 + j;
        if (row < N) {
            __half2 h01 = __floats2half2_rn(acc[j][0], acc[j][1]);
            __half2 h23 = __floats2half2_rn(acc[j][2], acc[j][3]);
            uint2 pk;
            pk.x = *(unsigned int*)&h01;
            pk.y = *(unsigned int*)&h23;
            *((uint2*)(H + (size_t)row * 64 + c0)) = pk;
        }
    }
}

// ---- fused agg + next-layer GEMM (FC=0) or agg + final FC (FC=1) ----
// Round-2 structure, 32-row tiles: 1563 blocks (~6/CU) to double resident waves
// during the gather phase (tests wave-count-MLP hypothesis). Each wave handles
// 8 concurrent nodes (group g = lane>>3 owns a node; lane slot l = lane&7 owns
// channels 8l..8l+7, one uint4 = 128B row gather per edge). Summation order per
// channel identical to round-2.
template<int FC>
__global__ __launch_bounds__(256, 6)
void k_agg_gemm(const uint4* __restrict__ H4, const int* __restrict__ rp,
                const int* __restrict__ bsum, const int* __restrict__ deg,
                const int* __restrict__ col, const float* __restrict__ nd,
                const float* __restrict__ nsrc, const float* __restrict__ bias,
                const float* __restrict__ W, const float* __restrict__ Wb2,
                void* __restrict__ OutP, int N) {
    __shared__ float Xs[32 * XS_STRIDE];
    __shared__ float Ws[FC ? 680 : 4096];   // FC=1: stride-68 transposed (bank-safe)
    __shared__ float Wb[16];
    int tid = threadIdx.x;

    if constexpr (FC == 0) {
        for (int i = tid; i < 1024; i += 256)
            ((float4*)Ws)[i] = ((const float4*)W)[i];
    } else {
        for (int i = tid; i < 640; i += 256) {   // Ws[c*68+k] = Wfc[k][c]
            int k = i / 10, c = i - k * 10;
            Ws[c * 68 + k] = W[i];
        }
        if (tid < 10) Wb[tid] = Wb2[tid];
    }

    int wave = tid >> 6;
    int lane = tid & 63;
    int g = lane >> 3;   // node sub-index (8 nodes in flight per wave)
    int l = lane & 7;    // uint4 slot: channels 8l..8l+7
    int rowBase = blockIdx.x * 32;

    float4 bv0 = *((const float4*)&bias[l * 8]);
    float4 bv1 = *((const float4*)&bias[l * 8 + 4]);

    // ---- phase A: one round of 8 concurrent nodes per wave (4 waves x 8 = 32)
    int node = rowBase + wave * 8 + g;
    int st = 0, n = 0; float nv = 0.f, nsv = 0.f;
    if (node < N) {
        st  = rp[node] + bsum[node >> 8];
        n   = deg[node];
        nv  = nd[node];
        if constexpr (FC == 0) nsv = nsrc[node];
    }
    int idx = (l < n) ? col[st + l] : 0;

    // wave-uniform loop bound (max deg across the 8 groups)
    int m = n;
#pragma unroll
    for (int d = 8; d <= 32; d <<= 1) {
        int tm = __shfl_xor(m, d); m = m > tm ? m : tm;
    }

    {
        float acc[8] = {0.f, 0.f, 0.f, 0.f, 0.f, 0.f, 0.f, 0.f};
        for (int j0 = 0; j0 < m; j0 += 8) {
            int idxn = ((j0 + 8 + l) < n) ? col[st + j0 + 8 + l] : 0;
#pragma unroll
            for (int jj = 0; jj < 8; jj++) {
                int s = __shfl(idx, (g << 3) + jj);
                if (j0 + jj < n) {
                    uint4 v = H4[(size_t)s * 8 + l];
                    float2 f0 = __half22float2(*(__half2*)&v.x);
                    float2 f1 = __half22float2(*(__half2*)&v.y);
                    float2 f2 = __half22float2(*(__half2*)&v.z);
                    float2 f3 = __half22float2(*(__half2*)&v.w);
                    acc[0] += f0.x; acc[1] += f0.y; acc[2] += f1.x; acc[3] += f1.y;
                    acc[4] += f2.x; acc[5] += f2.y; acc[6] += f3.x; acc[7] += f3.y;
                }
            }
            idx = idxn;
        }
        float4 o0, o1;
        o0.x = tanhf(acc[0] * nv + bv0.x);
        o0.y = tanhf(acc[1] * nv + bv0.y);
        o0.z = tanhf(acc[2] * nv + bv0.z);
        o0.w = tanhf(acc[3] * nv + bv0.w);
        o1.x = tanhf(acc[4] * nv + bv1.x);
        o1.y = tanhf(acc[5] * nv + bv1.y);
        o1.z = tanhf(acc[6] * nv + bv1.z);
        o1.w = tanhf(acc[7] * nv + bv1.w);
        if constexpr (FC == 0) {   // pre-scale by ns for next GEMM
            o0.x *= nsv; o0.y *= nsv; o0.z *= nsv; o0.w *= nsv;
            o1.x *= nsv; o1.y *= nsv; o1.z *= nsv; o1.w *= nsv;
        }
        if (node >= N) {
            o0 = make_float4(0.f, 0.f, 0.f, 0.f);
            o1 = make_float4(0.f, 0.f, 0.f, 0.f);
        }
        int row = wave * 8 + g;
        *((float4*)&Xs[row * XS_STRIDE + l * 8])     = o0;
        *((float4*)&Xs[row * XS_STRIDE + l * 8 + 4]) = o1;
    }
    __syncthreads();

    // ---- phase B
    if constexpr (FC == 0) {
        __half* Hh = (__half*)OutP;
        int tc = tid & 15, tr = tid >> 4;
        int c0 = tc * 4, r0 = tr * 2;      // 16 thread-rows x 2 rows = 32
        float acc[2][4] = {};

#pragma unroll 2
        for (int k = 0; k < 64; k += 4) {
            float4 wv[4];
#pragma unroll
            for (int kk = 0; kk < 4; kk++)
                wv[kk] = *((const float4*)&Ws[(k + kk) * 64 + c0]);
#pragma unroll
            for (int j = 0; j < 2; j++) {
                float4 xv = *((const float4*)&Xs[(r0 + j) * XS_STRIDE + k]);
                acc[j][0] += xv.x * wv[0].x; acc[j][1] += xv.x * wv[0].y;
                acc[j][2] += xv.x * wv[0].z; acc[j][3] += xv.x * wv[0].w;
                acc[j][0] += xv.y * wv[1].x; acc[j][1] += xv.y * wv[1].y;
                acc[j][2] += xv.y * wv[1].z; acc[j][3] += xv.y * wv[1].w;
                acc[j][0] += xv.z * wv[2].x; acc[j][1] += xv.z * wv[2].y;
                acc[j][2] += xv.z * wv[2].z; acc[j][3] += xv.z * wv[2].w;
                acc[j][0] += xv.w * wv[3].x; acc[j][1] += xv.w * wv[3].y;
                acc[j][2] += xv.w * wv[3].z; acc[j][3] += xv.w * wv[3].w;
            }
        }
#pragma unroll
        for (int j = 0; j < 2; j++) {
            int row = rowBase + r0 + j;
            if (row < N) {
                __half2 h01 = __floats2half2_rn(acc[j][0], acc[j][1]);
                __half2 h23 = __floats2half2_rn(acc[j][2], acc[j][3]);
                uint2 pk;
                pk.x = *(unsigned int*)&h01;
                pk.y = *(unsigned int*)&h23;
                *((uint2*)(Hh + (size_t)row * 64 + c0)) = pk;
            }
        }
    } else {
        float* outF = (float*)OutP;
        for (int idx2 = tid; idx2 < 320; idx2 += 256) {
            int ln = idx2 / 10;
            int cl = idx2 - ln * 10;
            float acc = Wb[cl];
#pragma unroll
            for (int k = 0; k < 64; k += 4) {
                float4 xv = *((const float4*)&Xs[ln * XS_STRIDE + k]);
                float4 wv = *((const float4*)&Ws[cl * 68 + k]);
                acc += xv.x * wv.x + xv.y * wv.y + xv.z * wv.z + xv.w * wv.w;
            }
            int row = rowBase + ln;
            if (row < N) outF[(size_t)row * 10 + cl] = acc;
        }
    }
}

extern "C" void kernel_launch(void* const* d_in, const int* in_sizes, int n_in,
                              void* d_out, int out_size, void* d_ws, size_t ws_size,
                              hipStream_t stream) {
    const float* x   = (const float*)d_in[0];
    const int*   src = (const int*)d_in[1];
    const int*   dst = (const int*)d_in[2];
    const float* W1  = (const float*)d_in[3];
    const float* b1  = (const float*)d_in[4];
    const float* W2  = (const float*)d_in[5];
    const float* b2  = (const float*)d_in[6];
    const float* W3  = (const float*)d_in[7];
    const float* b3  = (const float*)d_in[8];
    const float* Wfc = (const float*)d_in[9];
    const float* bfc = (const float*)d_in[10];
    float* out = (float*)d_out;
    int N = in_sizes[0] / 64;
    int E = in_sizes[1];
    int P = (E + CHUNK - 1) >> CHUNK_SHIFT;
    int words = (N + 3) / 4;

    char* ws = (char*)d_ws;
    size_t p = 0;
    auto alloc = [&](size_t bytes) -> void* {
        void* r = ws + p;
        p = (p + bytes + 255) & ~(size_t)255;
        return r;
    };
    int*    deg_d = (int*)alloc((size_t)N * 4);
    int*    rp    = (int*)alloc((size_t)N * 4);
    int*    bsum  = (int*)alloc((size_t)THREADS * 4);
    unsigned char* rank = (unsigned char*)alloc((size_t)E);
    int*    col   = (int*)alloc((size_t)E * 4);
    float*  ns    = (float*)alloc((size_t)N * 4);
    float*  nd    = (float*)alloc((size_t)N * 4);
    unsigned int* partS = (unsigned int*)alloc((size_t)P * words * 4);
    unsigned int* partD = (unsigned int*)alloc((size_t)P * words * 4);
    unsigned int* prefD = (unsigned int*)alloc((size_t)P * words * 4);
    __half* bufH  = (__half*)alloc((size_t)N * 64 * 2);
    __half* bufH2 = (__half*)alloc((size_t)N * 64 * 2);
    unsigned int* counter = (unsigned int*)alloc(4);
    (void)ws_size; (void)n_in; (void)out_size;

    int gFill = (E + 255) / 256;
    int gP = (words + 63) / 64;
    int gGemm = (N + 63) / 64;     // layer-1 GEMM tiles (64 rows)
    int gAgg  = (N + 31) / 32;     // agg tiles (32 rows -> ~6 blocks/CU)

    k_hist<<<2 * P, 1024, 0, stream>>>(src, dst, partS, partD, rank, counter, E, P, words);
    k_pre <<<gP, THREADS, 0, stream>>>(partS, partD, prefD, deg_d, ns, nd,
                                       rp, bsum, counter, P, words, N);
    k_fill_gemm<<<gFill + gGemm, 256, 0, stream>>>(src, dst, rp, bsum, rank, prefD,
                                                   col, E, words, gFill,
                                                   x, ns, W1, bufH, N);
    k_agg_gemm<0><<<gAgg, 256, 0, stream>>>((const uint4*)bufH,  rp, bsum, deg_d, col,
                                            nd, ns, b1, W2, nullptr, bufH2, N);
    k_agg_gemm<0><<<gAgg, 256, 0, stream>>>((const uint4*)bufH2, rp, bsum, deg_d, col,
                                            nd, ns, b2, W3, nullptr, bufH, N);
    k_agg_gemm<1><<<gAgg, 256, 0, stream>>>((const uint4*)bufH,  rp, bsum, deg_d, col,
                                            nd, ns, b3, Wfc, bfc, out, N);
}

// Round 7
// 187.572 us; speedup vs baseline: 5.1003x; 1.0656x over previous
//
#include <hip/hip_runtime.h>
#include <hip/hip_fp16.h>
#include <math.h>

#define THREADS 256
#define CHUNK_SHIFT 15
#define CHUNK (1 << CHUNK_SHIFT)
#define LDS_WORDS 12500   // ceil(N/4) for N=50000, 8-bit packed counters
#define MAXB 16           // max chunks per quarter in k_pre (holds for P <= 64)
#define XS_STRIDE 68

// ---- privatized LDS histogram, 4 bins/word (8-bit); dst blocks capture rank ----
__global__ __launch_bounds__(1024)
void k_hist(const int* __restrict__ src, const int* __restrict__ dst,
            unsigned int* __restrict__ partS, unsigned int* __restrict__ partD,
            unsigned char* __restrict__ rank, unsigned int* __restrict__ counter,
            int E, int P, int words) {
    __shared__ unsigned int hist[LDS_WORDS];
    if (blockIdx.x == 0 && threadIdx.x == 0) *counter = 0u;
    int isSrc = (blockIdx.x >= (unsigned)P);
    int b = isSrc ? (blockIdx.x - P) : blockIdx.x;
    int tid = threadIdx.x;

    for (int w = tid; w < words; w += 1024) hist[w] = 0u;
    __syncthreads();

    int start = b << CHUNK_SHIFT;
    int end = start + CHUNK; if (end > E) end = E;

    if (isSrc) {
        for (int e = start + tid; e < end; e += 1024) {
            int s = src[e];
            atomicAdd(&hist[s >> 2], 1u << ((s & 3) * 8));
        }
    } else {
        for (int e = start + tid; e < end; e += 1024) {
            int d = dst[e];
            unsigned int old = atomicAdd(&hist[d >> 2], 1u << ((d & 3) * 8));
            rank[e] = (unsigned char)((old >> ((d & 3) * 8)) & 0xFFu);
        }
    }
    __syncthreads();

    unsigned int* part = isSrc ? partS : partD;
    for (int w = tid; w < words; w += 1024)
        part[(size_t)b * words + w] = hist[w];
}

// ---- k_pre: one packed word (4 nodes) per thread, chunk range split 4-way ----
__global__ __launch_bounds__(THREADS)
void k_pre(const unsigned int* __restrict__ partS,
           const unsigned int* __restrict__ partD,
           unsigned int* __restrict__ prefD,
           int* __restrict__ deg_d, float* __restrict__ ns, float* __restrict__ nd,
           int* __restrict__ rp, int* __restrict__ bsum,
           unsigned int* __restrict__ counter,
           int P, int words, int N) {
    __shared__ unsigned int qsD[4][64];
    __shared__ unsigned int qsS[4][64];
    int t = threadIdx.x;
    int widx = t & 63;
    int q = t >> 6;
    int w = blockIdx.x * 64 + widx;
    bool valid = (w < words);

    int per = (P + 3) >> 2;
    int blo = q * per;
    int cnt = P - blo; if (cnt > per) cnt = per; if (cnt < 0) cnt = 0;

    unsigned int vD[MAXB];
    unsigned int runD = 0, runS = 0;
#pragma unroll
    for (int bb = 0; bb < MAXB; bb++) {
        unsigned int vd = 0, vs = 0;
        if (bb < cnt && valid) {
            size_t off = (size_t)(blo + bb) * words + w;
            vd = partD[off];
            vs = partS[off];
        }
        vD[bb] = vd;
        runD += vd;
        runS += vs;
    }
    qsD[q][widx] = runD;
    qsS[q][widx] = runS;
    __syncthreads();

    unsigned int baseD = 0, totD = 0, totS = 0;
#pragma unroll
    for (int qq = 0; qq < 4; qq++) {
        unsigned int xd = qsD[qq][widx];
        unsigned int xs = qsS[qq][widx];
        if (qq < q) baseD += xd;
        totD += xd;
        totS += xs;
    }

    unsigned int pref = baseD;
#pragma unroll
    for (int bb = 0; bb < MAXB; bb++) {
        if (bb < cnt && valid)
            prefD[(size_t)(blo + bb) * words + w] = pref;
        pref += vD[bb];
    }

    if (q == 0) {
        int b0 = (int)(totD & 0xFFu), b1 = (int)((totD >> 8) & 0xFFu),
            b2 = (int)((totD >> 16) & 0xFFu), b3 = (int)((totD >> 24) & 0xFFu);
        int wsum = b0 + b1 + b2 + b3;
        int incl = wsum;
#pragma unroll
        for (int off = 1; off < 64; off <<= 1) {
            int y = __shfl_up(incl, off);
            if (widx >= off) incl += y;
        }
        int excl = incl - wsum;
        int btot = __shfl(incl, 63);
        if (widx == 0)
            bsum[blockIdx.x] = (int)atomicAdd(counter, (unsigned int)btot);
        if (valid) {
            int s0 = (int)(totS & 0xFFu), s1 = (int)((totS >> 8) & 0xFFu),
                s2 = (int)((totS >> 16) & 0xFFu), s3 = (int)((totS >> 24) & 0xFFu);
            int4 dv; dv.x = b0; dv.y = b1; dv.z = b2; dv.w = b3;
            *(int4*)&deg_d[(size_t)4 * w] = dv;
            float4 ndv;
            ndv.x = b0 ? 1.0f / sqrtf((float)b0) : 0.0f;
            ndv.y = b1 ? 1.0f / sqrtf((float)b1) : 0.0f;
            ndv.z = b2 ? 1.0f / sqrtf((float)b2) : 0.0f;
            ndv.w = b3 ? 1.0f / sqrtf((float)b3) : 0.0f;
            *(float4*)&nd[(size_t)4 * w] = ndv;
            float4 nsv;
            nsv.x = s0 ? 1.0f / sqrtf((float)s0) : 0.0f;
            nsv.y = s1 ? 1.0f / sqrtf((float)s1) : 0.0f;
            nsv.z = s2 ? 1.0f / sqrtf((float)s2) : 0.0f;
            nsv.w = s3 ? 1.0f / sqrtf((float)s3) : 0.0f;
            *(float4*)&ns[(size_t)4 * w] = nsv;
            int4 rv; rv.x = excl; rv.y = excl + b0;
            rv.z = excl + b0 + b1; rv.w = excl + b0 + b1 + b2;
            *(int4*)&rp[(size_t)4 * w] = rv;
        }
    }
}

// ---- merged: CSR fill (blocks [0,gFill)) || layer-1 GEMM (blocks [gFill, ...)) ----
__global__ __launch_bounds__(256, 4)
void k_fill_gemm(const int* __restrict__ src, const int* __restrict__ dst,
                 const int* __restrict__ rp, const int* __restrict__ bsum,
                 const unsigned char* __restrict__ rank,
                 const unsigned int* __restrict__ prefD,
                 int* __restrict__ col, int E, int words, int gFill,
                 const float* __restrict__ X, const float* __restrict__ norm,
                 const float* __restrict__ W, __half* __restrict__ H, int N) {
    __shared__ float Xs[64 * XS_STRIDE];
    __shared__ float Ws[64 * 64];
    int tid = threadIdx.x;

    if ((int)blockIdx.x < gFill) {
        int e = blockIdx.x * 256 + tid;
        if (e < E) {
            int d = dst[e];
            int b = e >> CHUNK_SHIFT;
            unsigned int pk = prefD[(size_t)b * words + (d >> 2)];
            int pref = (int)((pk >> ((d & 3) * 8)) & 0xFFu);
            col[rp[d] + bsum[d >> 8] + pref + (int)rank[e]] = src[e];
        }
        return;
    }

    int rowBase = ((int)blockIdx.x - gFill) * 64;
    for (int i = tid; i < 1024; i += 256)
        ((float4*)Ws)[i] = ((const float4*)W)[i];
    for (int i = tid; i < 1024; i += 256) {
        int r = i >> 4, k4 = i & 15;
        int row = rowBase + r;
        float4 v = make_float4(0.f, 0.f, 0.f, 0.f);
        if (row < N) {
            v = ((const float4*)X)[(size_t)row * 16 + k4];
            float nv = norm[row];
            v.x *= nv; v.y *= nv; v.z *= nv; v.w *= nv;
        }
        *((float4*)&Xs[r * XS_STRIDE + (k4 << 2)]) = v;
    }
    __syncthreads();

    int tc = tid & 15, tr = tid >> 4;
    int c0 = tc * 4, r0 = tr * 4;
    float acc[4][4] = {};

#pragma unroll 2
    for (int k = 0; k < 64; k += 4) {
        float4 wv[4];
#pragma unroll
        for (int kk = 0; kk < 4; kk++)
            wv[kk] = *((const float4*)&Ws[(k + kk) * 64 + c0]);
#pragma unroll
        for (int j = 0; j < 4; j++) {
            float4 xv = *((const float4*)&Xs[(r0 + j) * XS_STRIDE + k]);
            acc[j][0] += xv.x * wv[0].x; acc[j][1] += xv.x * wv[0].y;
            acc[j][2] += xv.x * wv[0].z; acc[j][3] += xv.x * wv[0].w;
            acc[j][0] += xv.y * wv[1].x; acc[j][1] += xv.y * wv[1].y;
            acc[j][2] += xv.y * wv[1].z; acc[j][3] += xv.y * wv[1].w;
            acc[j][0] += xv.z * wv[2].x; acc[j][1] += xv.z * wv[2].y;
            acc[j][2] += xv.z * wv[2].z; acc[j][3] += xv.z * wv[2].w;
            acc[j][0] += xv.w * wv[3].x; acc[j][1] += xv.w * wv[3].y;
            acc[j][2] += xv.w * wv[3].z; acc[j][3] += xv.w * wv[3].w;
        }
    }
#pragma unroll
    for (int j = 0; j < 4; j++) {
        int row = rowBase + r0 + j;
        if (row < N) {
            __half2 h01 = __floats2half2_rn(acc[j][0], acc[j][1]);
            __half2 h23 = __floats2half2_rn(acc[j][2], acc[j][3]);
            uint2 pk;
            pk.x = *(unsigned int*)&h01;
            pk.y = *(unsigned int*)&h23;
            *((uint2*)(H + (size_t)row * 64 + c0)) = pk;
        }
    }
}

// ---- fused agg + next-layer GEMM (FC=0) or agg + final FC (FC=1) ----
// 512-thread blocks, 64-row tiles, 4 blocks/CU x 8 waves = 32 waves/CU (max).
// BARRIER-FREE after Ws staging: each wave aggregates its own 8 nodes into its
// own Xs rows, then GEMMs those rows itself (lane (g,l): row g, cols 8l..8l+7;
// x-reads broadcast across same-g lanes, Ws-reads broadcast across same-l lanes).
// No A->B __syncthreads -> no straggler coupling across waves.
template<int FC>
__global__ __launch_bounds__(512)
void k_agg_gemm(const uint4* __restrict__ H4, const int* __restrict__ rp,
                const int* __restrict__ bsum, const int* __restrict__ deg,
                const int* __restrict__ col, const float* __restrict__ nd,
                const float* __restrict__ nsrc, const float* __restrict__ bias,
                const float* __restrict__ W, const float* __restrict__ Wb2,
                void* __restrict__ OutP, int N) {
    __shared__ float Xs[64 * XS_STRIDE];
    __shared__ float Ws[FC ? 680 : 4096];   // FC=1: stride-68 transposed (bank-safe)
    __shared__ float Wb[16];
    int tid = threadIdx.x;

    if constexpr (FC == 0) {
        for (int i = tid; i < 1024; i += 512)
            ((float4*)Ws)[i] = ((const float4*)W)[i];
    } else {
        for (int i = tid; i < 640; i += 512) {   // Ws[c*68+k] = Wfc[k][c]
            int k = i / 10, c = i - k * 10;
            Ws[c * 68 + k] = W[i];
        }
        if (tid < 10) Wb[tid] = Wb2[tid];
    }
    __syncthreads();   // the ONLY block-wide barrier

    int wave = tid >> 6;
    int lane = tid & 63;
    int g = lane >> 3;   // node sub-index (8 nodes in flight per wave)
    int l = lane & 7;    // uint4 slot: channels 8l..8l+7
    int rowBase = blockIdx.x * 64;
    int row = wave * 8 + g;          // this lane's Xs row (local)

    float4 bv0 = *((const float4*)&bias[l * 8]);
    float4 bv1 = *((const float4*)&bias[l * 8 + 4]);

    // ---- phase A: 8 concurrent nodes per wave
    int node = rowBase + row;
    int st = 0, n = 0; float nv = 0.f, nsv = 0.f;
    if (node < N) {
        st  = rp[node] + bsum[node >> 8];
        n   = deg[node];
        nv  = nd[node];
        if constexpr (FC == 0) nsv = nsrc[node];
    }
    int idx = (l < n) ? col[st + l] : 0;

    // wave-uniform loop bound (max deg across the wave's 8 nodes)
    int m = n;
#pragma unroll
    for (int d = 8; d <= 32; d <<= 1) {
        int tm = __shfl_xor(m, d); m = m > tm ? m : tm;
    }

    {
        float acc[8] = {0.f, 0.f, 0.f, 0.f, 0.f, 0.f, 0.f, 0.f};
        for (int j0 = 0; j0 < m; j0 += 8) {
            int idxn = ((j0 + 8 + l) < n) ? col[st + j0 + 8 + l] : 0;
#pragma unroll
            for (int jj = 0; jj < 8; jj++) {
                int s = __shfl(idx, (g << 3) + jj);
                if (j0 + jj < n) {
                    uint4 v = H4[(size_t)s * 8 + l];
                    float2 f0 = __half22float2(*(__half2*)&v.x);
                    float2 f1 = __half22float2(*(__half2*)&v.y);
                    float2 f2 = __half22float2(*(__half2*)&v.z);
                    float2 f3 = __half22float2(*(__half2*)&v.w);
                    acc[0] += f0.x; acc[1] += f0.y; acc[2] += f1.x; acc[3] += f1.y;
                    acc[4] += f2.x; acc[5] += f2.y; acc[6] += f3.x; acc[7] += f3.y;
                }
            }
            idx = idxn;
        }
        float4 o0, o1;
        o0.x = tanhf(acc[0] * nv + bv0.x);
        o0.y = tanhf(acc[1] * nv + bv0.y);
        o0.z = tanhf(acc[2] * nv + bv0.z);
        o0.w = tanhf(acc[3] * nv + bv0.w);
        o1.x = tanhf(acc[4] * nv + bv1.x);
        o1.y = tanhf(acc[5] * nv + bv1.y);
        o1.z = tanhf(acc[6] * nv + bv1.z);
        o1.w = tanhf(acc[7] * nv + bv1.w);
        if constexpr (FC == 0) {   // pre-scale by ns for next GEMM
            o0.x *= nsv; o0.y *= nsv; o0.z *= nsv; o0.w *= nsv;
            o1.x *= nsv; o1.y *= nsv; o1.z *= nsv; o1.w *= nsv;
        }
        if (node >= N) {
            o0 = make_float4(0.f, 0.f, 0.f, 0.f);
            o1 = make_float4(0.f, 0.f, 0.f, 0.f);
        }
        *((float4*)&Xs[row * XS_STRIDE + l * 8])     = o0;
        *((float4*)&Xs[row * XS_STRIDE + l * 8 + 4]) = o1;
    }
    // NO __syncthreads: each wave consumes only its own Xs rows below
    // (same-wave LDS RAW; compiler inserts lgkmcnt waits).

    // ---- phase B (per-wave)
    if constexpr (FC == 0) {
        __half* Hh = (__half*)OutP;
        // lane (g,l): output row 'row', cols 8l..8l+7
        float a2[8] = {0.f, 0.f, 0.f, 0.f, 0.f, 0.f, 0.f, 0.f};
#pragma unroll 2
        for (int k = 0; k < 64; k += 4) {
            float4 xv = *((const float4*)&Xs[row * XS_STRIDE + k]);
#pragma unroll
            for (int kk = 0; kk < 4; kk++) {
                float4 w0 = *((const float4*)&Ws[(k + kk) * 64 + l * 8]);
                float4 w1 = *((const float4*)&Ws[(k + kk) * 64 + l * 8 + 4]);
                float xk = (kk == 0) ? xv.x : (kk == 1) ? xv.y : (kk == 2) ? xv.z : xv.w;
                a2[0] += xk * w0.x; a2[1] += xk * w0.y;
                a2[2] += xk * w0.z; a2[3] += xk * w0.w;
                a2[4] += xk * w1.x; a2[5] += xk * w1.y;
                a2[6] += xk * w1.z; a2[7] += xk * w1.w;
            }
        }
        int grow = rowBase + row;
        if (grow < N) {
            __half2 h0 = __floats2half2_rn(a2[0], a2[1]);
            __half2 h1 = __floats2half2_rn(a2[2], a2[3]);
            __half2 h2 = __floats2half2_rn(a2[4], a2[5]);
            __half2 h3 = __floats2half2_rn(a2[6], a2[7]);
            uint4 pk;
            pk.x = *(unsigned int*)&h0;
            pk.y = *(unsigned int*)&h1;
            pk.z = *(unsigned int*)&h2;
            pk.w = *(unsigned int*)&h3;
            *((uint4*)(Hh + (size_t)grow * 64 + l * 8)) = pk;
        }
    } else {
        float* outF = (float*)OutP;
        // wave covers its 8 rows x 10 cols = 80 outputs, 2 passes of 64 lanes
        for (int t2 = lane; t2 < 80; t2 += 64) {
            int ln = t2 / 10;
            int cl = t2 - ln * 10;
            int lrow = wave * 8 + ln;
            float acc = Wb[cl];
#pragma unroll
            for (int k = 0; k < 64; k += 4) {
                float4 xv = *((const float4*)&Xs[lrow * XS_STRIDE + k]);
                float4 wv = *((const float4*)&Ws[cl * 68 + k]);
                acc += xv.x * wv.x + xv.y * wv.y + xv.z * wv.z + xv.w * wv.w;
            }
            int grow = rowBase + lrow;
            if (grow < N) outF[(size_t)grow * 10 + cl] = acc;
        }
    }
}

extern "C" void kernel_launch(void* const* d_in, const int* in_sizes, int n_in,
                              void* d_out, int out_size, void* d_ws, size_t ws_size,
                              hipStream_t stream) {
    const float* x   = (const float*)d_in[0];
    const int*   src = (const int*)d_in[1];
    const int*   dst = (const int*)d_in[2];
    const float* W1  = (const float*)d_in[3];
    const float* b1  = (const float*)d_in[4];
    const float* W2  = (const float*)d_in[5];
    const float* b2  = (const float*)d_in[6];
    const float* W3  = (const float*)d_in[7];
    const float* b3  = (const float*)d_in[8];
    const float* Wfc = (const float*)d_in[9];
    const float* bfc = (const float*)d_in[10];
    float* out = (float*)d_out;
    int N = in_sizes[0] / 64;
    int E = in_sizes[1];
    int P = (E + CHUNK - 1) >> CHUNK_SHIFT;
    int words = (N + 3) / 4;

    char* ws = (char*)d_ws;
    size_t p = 0;
    auto alloc = [&](size_t bytes) -> void* {
        void* r = ws + p;
        p = (p + bytes + 255) & ~(size_t)255;
        return r;
    };
    int*    deg_d = (int*)alloc((size_t)N * 4);
    int*    rp    = (int*)alloc((size_t)N * 4);
    int*    bsum  = (int*)alloc((size_t)THREADS * 4);
    unsigned char* rank = (unsigned char*)alloc((size_t)E);
    int*    col   = (int*)alloc((size_t)E * 4);
    float*  ns    = (float*)alloc((size_t)N * 4);
    float*  nd    = (float*)alloc((size_t)N * 4);
    unsigned int* partS = (unsigned int*)alloc((size_t)P * words * 4);
    unsigned int* partD = (unsigned int*)alloc((size_t)P * words * 4);
    unsigned int* prefD = (unsigned int*)alloc((size_t)P * words * 4);
    __half* bufH  = (__half*)alloc((size_t)N * 64 * 2);
    __half* bufH2 = (__half*)alloc((size_t)N * 64 * 2);
    unsigned int* counter = (unsigned int*)alloc(4);
    (void)ws_size; (void)n_in; (void)out_size;

    int gFill = (E + 255) / 256;
    int gP = (words + 63) / 64;
    int gGemm = (N + 63) / 64;     // layer-1 GEMM tiles (64 rows)
    int gAgg  = (N + 63) / 64;     // agg tiles (64 rows, 512-thread blocks)

    k_hist<<<2 * P, 1024, 0, stream>>>(src, dst, partS, partD, rank, counter, E, P, words);
    k_pre <<<gP, THREADS, 0, stream>>>(partS, partD, prefD, deg_d, ns, nd,
                                       rp, bsum, counter, P, words, N);
    k_fill_gemm<<<gFill + gGemm, 256, 0, stream>>>(src, dst, rp, bsum, rank, prefD,
                                                   col, E, words, gFill,
                                                   x, ns, W1, bufH, N);
    k_agg_gemm<0><<<gAgg, 512, 0, stream>>>((const uint4*)bufH,  rp, bsum, deg_d, col,
                                            nd, ns, b1, W2, nullptr, bufH2, N);
    k_agg_gemm<0><<<gAgg, 512, 0, stream>>>((const uint4*)bufH2, rp, bsum, deg_d, col,
                                            nd, ns, b2, W3, nullptr, bufH, N);
    k_agg_gemm<1><<<gAgg, 512, 0, stream>>>((const uint4*)bufH,  rp, bsum, deg_d, col,
                                            nd, ns, b3, Wfc, bfc, out, N);
}

// Round 8
// 185.372 us; speedup vs baseline: 5.1609x; 1.0119x over previous
//
#include <hip/hip_runtime.h>
#include <hip/hip_fp16.h>
#include <math.h>

#define THREADS 256
#define CHUNK_SHIFT 15
#define CHUNK (1 << CHUNK_SHIFT)
#define LDS_WORDS 12500   // ceil(N/4) for N=50000, 8-bit packed counters (50 KB)
#define MAXB 16           // max chunks per quarter in k_pre (holds for P <= 64)
#define XS_STRIDE 68

// ---- merged: privatized-LDS histogram (blocks [0,2P)) || raw layer-1 GEMM ----
// G = X @ W1 (fp32, NO ns scaling) is input-only -> runs concurrently with hist.
// LDS is a 50 KB union: hist bins OR (Xs 17.4 KB + Ws 16 KB). Hist blocks first
// in dispatch order so the critical path (hist -> k_pre) starts immediately.
__global__ __launch_bounds__(1024)
void k_hist_gemm(const int* __restrict__ src, const int* __restrict__ dst,
                 unsigned int* __restrict__ partS, unsigned int* __restrict__ partD,
                 unsigned char* __restrict__ rank, unsigned int* __restrict__ counter,
                 int E, int P, int words,
                 const float* __restrict__ X, const float* __restrict__ W,
                 float* __restrict__ G, int N) {
    __shared__ unsigned int lds_u[LDS_WORDS];
    int tid = threadIdx.x;
    int b = blockIdx.x;

    if (b < 2 * P) {
        // ---------------- histogram branch (identical to proven k_hist) --------
        unsigned int* hist = lds_u;
        if (b == 0 && tid == 0) *counter = 0u;
        int isSrc = (b >= P);
        int cb = isSrc ? (b - P) : b;

        for (int w = tid; w < words; w += 1024) hist[w] = 0u;
        __syncthreads();

        int start = cb << CHUNK_SHIFT;
        int end = start + CHUNK; if (end > E) end = E;

        if (isSrc) {
            for (int e = start + tid; e < end; e += 1024) {
                int s = src[e];
                atomicAdd(&hist[s >> 2], 1u << ((s & 3) * 8));
            }
        } else {
            for (int e = start + tid; e < end; e += 1024) {
                int d = dst[e];
                unsigned int old = atomicAdd(&hist[d >> 2], 1u << ((d & 3) * 8));
                rank[e] = (unsigned char)((old >> ((d & 3) * 8)) & 0xFFu);
            }
        }
        __syncthreads();

        unsigned int* part = isSrc ? partS : partD;
        for (int w = tid; w < words; w += 1024)
            part[(size_t)cb * words + w] = hist[w];
        return;
    }

    // ---------------- raw GEMM branch: G[row] = X[row] @ W ----------------
    float* Xs = (float*)lds_u;                    // 64 x 68
    float* Ws = ((float*)lds_u) + 64 * XS_STRIDE; // 64 x 64
    int rowBase = (b - 2 * P) * 64;

    ((float4*)Ws)[tid] = ((const float4*)W)[tid];        // 1024 float4 = all of W
    {
        int r = tid >> 4, k4 = tid & 15;
        int row = rowBase + r;
        float4 v = make_float4(0.f, 0.f, 0.f, 0.f);
        if (row < N) v = ((const float4*)X)[(size_t)row * 16 + k4];
        *((float4*)&Xs[r * XS_STRIDE + (k4 << 2)]) = v;
    }
    __syncthreads();

    int tc = tid & 15, tr = tid >> 4;     // thread: row tr, cols 4tc..4tc+3
    int c0 = tc * 4;
    float a0 = 0.f, a1 = 0.f, a2 = 0.f, a3 = 0.f;
#pragma unroll 4
    for (int k = 0; k < 64; k += 4) {
        float4 xv = *((const float4*)&Xs[tr * XS_STRIDE + k]);
        float4 w0 = *((const float4*)&Ws[(k + 0) * 64 + c0]);
        float4 w1 = *((const float4*)&Ws[(k + 1) * 64 + c0]);
        float4 w2 = *((const float4*)&Ws[(k + 2) * 64 + c0]);
        float4 w3 = *((const float4*)&Ws[(k + 3) * 64 + c0]);
        a0 += xv.x * w0.x; a1 += xv.x * w0.y; a2 += xv.x * w0.z; a3 += xv.x * w0.w;
        a0 += xv.y * w1.x; a1 += xv.y * w1.y; a2 += xv.y * w1.z; a3 += xv.y * w1.w;
        a0 += xv.z * w2.x; a1 += xv.z * w2.y; a2 += xv.z * w2.z; a3 += xv.z * w2.w;
        a0 += xv.w * w3.x; a1 += xv.w * w3.y; a2 += xv.w * w3.z; a3 += xv.w * w3.w;
    }
    int row = rowBase + tr;
    if (row < N)
        *((float4*)&G[(size_t)row * 64 + c0]) = make_float4(a0, a1, a2, a3);
}

// ---- k_pre: one packed word (4 nodes) per thread, chunk range split 4-way ----
__global__ __launch_bounds__(THREADS)
void k_pre(const unsigned int* __restrict__ partS,
           const unsigned int* __restrict__ partD,
           unsigned int* __restrict__ prefD,
           int* __restrict__ deg_d, float* __restrict__ ns, float* __restrict__ nd,
           int* __restrict__ rp, int* __restrict__ bsum,
           unsigned int* __restrict__ counter,
           int P, int words, int N) {
    __shared__ unsigned int qsD[4][64];
    __shared__ unsigned int qsS[4][64];
    int t = threadIdx.x;
    int widx = t & 63;
    int q = t >> 6;
    int w = blockIdx.x * 64 + widx;
    bool valid = (w < words);

    int per = (P + 3) >> 2;
    int blo = q * per;
    int cnt = P - blo; if (cnt > per) cnt = per; if (cnt < 0) cnt = 0;

    unsigned int vD[MAXB];
    unsigned int runD = 0, runS = 0;
#pragma unroll
    for (int bb = 0; bb < MAXB; bb++) {
        unsigned int vd = 0, vs = 0;
        if (bb < cnt && valid) {
            size_t off = (size_t)(blo + bb) * words + w;
            vd = partD[off];
            vs = partS[off];
        }
        vD[bb] = vd;
        runD += vd;
        runS += vs;
    }
    qsD[q][widx] = runD;
    qsS[q][widx] = runS;
    __syncthreads();

    unsigned int baseD = 0, totD = 0, totS = 0;
#pragma unroll
    for (int qq = 0; qq < 4; qq++) {
        unsigned int xd = qsD[qq][widx];
        unsigned int xs = qsS[qq][widx];
        if (qq < q) baseD += xd;
        totD += xd;
        totS += xs;
    }

    unsigned int pref = baseD;
#pragma unroll
    for (int bb = 0; bb < MAXB; bb++) {
        if (bb < cnt && valid)
            prefD[(size_t)(blo + bb) * words + w] = pref;
        pref += vD[bb];
    }

    if (q == 0) {
        int b0 = (int)(totD & 0xFFu), b1 = (int)((totD >> 8) & 0xFFu),
            b2 = (int)((totD >> 16) & 0xFFu), b3 = (int)((totD >> 24) & 0xFFu);
        int wsum = b0 + b1 + b2 + b3;
        int incl = wsum;
#pragma unroll
        for (int off = 1; off < 64; off <<= 1) {
            int y = __shfl_up(incl, off);
            if (widx >= off) incl += y;
        }
        int excl = incl - wsum;
        int btot = __shfl(incl, 63);
        if (widx == 0)
            bsum[blockIdx.x] = (int)atomicAdd(counter, (unsigned int)btot);
        if (valid) {
            int s0 = (int)(totS & 0xFFu), s1 = (int)((totS >> 8) & 0xFFu),
                s2 = (int)((totS >> 16) & 0xFFu), s3 = (int)((totS >> 24) & 0xFFu);
            int4 dv; dv.x = b0; dv.y = b1; dv.z = b2; dv.w = b3;
            *(int4*)&deg_d[(size_t)4 * w] = dv;
            float4 ndv;
            ndv.x = b0 ? 1.0f / sqrtf((float)b0) : 0.0f;
            ndv.y = b1 ? 1.0f / sqrtf((float)b1) : 0.0f;
            ndv.z = b2 ? 1.0f / sqrtf((float)b2) : 0.0f;
            ndv.w = b3 ? 1.0f / sqrtf((float)b3) : 0.0f;
            *(float4*)&nd[(size_t)4 * w] = ndv;
            float4 nsv;
            nsv.x = s0 ? 1.0f / sqrtf((float)s0) : 0.0f;
            nsv.y = s1 ? 1.0f / sqrtf((float)s1) : 0.0f;
            nsv.z = s2 ? 1.0f / sqrtf((float)s2) : 0.0f;
            nsv.w = s3 ? 1.0f / sqrtf((float)s3) : 0.0f;
            *(float4*)&ns[(size_t)4 * w] = nsv;
            int4 rv; rv.x = excl; rv.y = excl + b0;
            rv.z = excl + b0 + b1; rv.w = excl + b0 + b1 + b2;
            *(int4*)&rp[(size_t)4 * w] = rv;
        }
    }
}

// ---- merged: CSR fill (blocks [0,gFill)) || scale pass H = fp16(ns*G) ----
// No LDS -> high occupancy; both branches latency/BW-bound and independent.
__global__ __launch_bounds__(256)
void k_fill_scale(const int* __restrict__ src, const int* __restrict__ dst,
                  const int* __restrict__ rp, const int* __restrict__ bsum,
                  const unsigned char* __restrict__ rank,
                  const unsigned int* __restrict__ prefD,
                  int* __restrict__ col, int E, int words, int gFill,
                  const float* __restrict__ G, const float* __restrict__ norm,
                  __half* __restrict__ H, int N) {
    int tid = threadIdx.x;
    if ((int)blockIdx.x < gFill) {
        int e = blockIdx.x * 256 + tid;
        if (e < E) {
            int d = dst[e];
            int b = e >> CHUNK_SHIFT;
            unsigned int pk = prefD[(size_t)b * words + (d >> 2)];
            int pref = (int)((pk >> ((d & 3) * 8)) & 0xFFu);
            col[rp[d] + bsum[d >> 8] + pref + (int)rank[e]] = src[e];
        }
        return;
    }
    int i = ((int)blockIdx.x - gFill) * 256 + tid;   // one float4 (4 channels)
    if (i < N * 16) {
        int row = i >> 4;
        int k4 = i & 15;
        float nv = norm[row];
        float4 v = ((const float4*)G)[i];
        __half2 h01 = __floats2half2_rn(v.x * nv, v.y * nv);
        __half2 h23 = __floats2half2_rn(v.z * nv, v.w * nv);
        uint2 pk;
        pk.x = *(unsigned int*)&h01;
        pk.y = *(unsigned int*)&h23;
        *((uint2*)(H + (size_t)row * 64 + (k4 << 2))) = pk;
    }
}

// ---- fused agg + next-layer GEMM (FC=0) or agg + final FC (FC=1) ----
// 512-thread blocks, 64-row tiles, 32 waves/CU (max). Barrier-free after Ws
// staging: each wave aggregates its own 8 nodes and GEMMs its own Xs rows.
template<int FC>
__global__ __launch_bounds__(512)
void k_agg_gemm(const uint4* __restrict__ H4, const int* __restrict__ rp,
                const int* __restrict__ bsum, const int* __restrict__ deg,
                const int* __restrict__ col, const float* __restrict__ nd,
                const float* __restrict__ nsrc, const float* __restrict__ bias,
                const float* __restrict__ W, const float* __restrict__ Wb2,
                void* __restrict__ OutP, int N) {
    __shared__ float Xs[64 * XS_STRIDE];
    __shared__ float Ws[FC ? 680 : 4096];   // FC=1: stride-68 transposed (bank-safe)
    __shared__ float Wb[16];
    int tid = threadIdx.x;

    if constexpr (FC == 0) {
        for (int i = tid; i < 1024; i += 512)
            ((float4*)Ws)[i] = ((const float4*)W)[i];
    } else {
        for (int i = tid; i < 640; i += 512) {   // Ws[c*68+k] = Wfc[k][c]
            int k = i / 10, c = i - k * 10;
            Ws[c * 68 + k] = W[i];
        }
        if (tid < 10) Wb[tid] = Wb2[tid];
    }
    __syncthreads();   // the ONLY block-wide barrier

    int wave = tid >> 6;
    int lane = tid & 63;
    int g = lane >> 3;
    int l = lane & 7;
    int rowBase = blockIdx.x * 64;
    int row = wave * 8 + g;

    float4 bv0 = *((const float4*)&bias[l * 8]);
    float4 bv1 = *((const float4*)&bias[l * 8 + 4]);

    int node = rowBase + row;
    int st = 0, n = 0; float nv = 0.f, nsv = 0.f;
    if (node < N) {
        st  = rp[node] + bsum[node >> 8];
        n   = deg[node];
        nv  = nd[node];
        if constexpr (FC == 0) nsv = nsrc[node];
    }
    int idx = (l < n) ? col[st + l] : 0;

    int m = n;
#pragma unroll
    for (int d = 8; d <= 32; d <<= 1) {
        int tm = __shfl_xor(m, d); m = m > tm ? m : tm;
    }

    {
        float acc[8] = {0.f, 0.f, 0.f, 0.f, 0.f, 0.f, 0.f, 0.f};
        for (int j0 = 0; j0 < m; j0 += 8) {
            int idxn = ((j0 + 8 + l) < n) ? col[st + j0 + 8 + l] : 0;
#pragma unroll
            for (int jj = 0; jj < 8; jj++) {
                int s = __shfl(idx, (g << 3) + jj);
                if (j0 + jj < n) {
                    uint4 v = H4[(size_t)s * 8 + l];
                    float2 f0 = __half22float2(*(__half2*)&v.x);
                    float2 f1 = __half22float2(*(__half2*)&v.y);
                    float2 f2 = __half22float2(*(__half2*)&v.z);
                    float2 f3 = __half22float2(*(__half2*)&v.w);
                    acc[0] += f0.x; acc[1] += f0.y; acc[2] += f1.x; acc[3] += f1.y;
                    acc[4] += f2.x; acc[5] += f2.y; acc[6] += f3.x; acc[7] += f3.y;
                }
            }
            idx = idxn;
        }
        float4 o0, o1;
        o0.x = tanhf(acc[0] * nv + bv0.x);
        o0.y = tanhf(acc[1] * nv + bv0.y);
        o0.z = tanhf(acc[2] * nv + bv0.z);
        o0.w = tanhf(acc[3] * nv + bv0.w);
        o1.x = tanhf(acc[4] * nv + bv1.x);
        o1.y = tanhf(acc[5] * nv + bv1.y);
        o1.z = tanhf(acc[6] * nv + bv1.z);
        o1.w = tanhf(acc[7] * nv + bv1.w);
        if constexpr (FC == 0) {
            o0.x *= nsv; o0.y *= nsv; o0.z *= nsv; o0.w *= nsv;
            o1.x *= nsv; o1.y *= nsv; o1.z *= nsv; o1.w *= nsv;
        }
        if (node >= N) {
            o0 = make_float4(0.f, 0.f, 0.f, 0.f);
            o1 = make_float4(0.f, 0.f, 0.f, 0.f);
        }
        *((float4*)&Xs[row * XS_STRIDE + l * 8])     = o0;
        *((float4*)&Xs[row * XS_STRIDE + l * 8 + 4]) = o1;
    }
    // NO __syncthreads: each wave consumes only its own Xs rows below.

    if constexpr (FC == 0) {
        __half* Hh = (__half*)OutP;
        float a2[8] = {0.f, 0.f, 0.f, 0.f, 0.f, 0.f, 0.f, 0.f};
#pragma unroll 2
        for (int k = 0; k < 64; k += 4) {
            float4 xv = *((const float4*)&Xs[row * XS_STRIDE + k]);
#pragma unroll
            for (int kk = 0; kk < 4; kk++) {
                float4 w0 = *((const float4*)&Ws[(k + kk) * 64 + l * 8]);
                float4 w1 = *((const float4*)&Ws[(k + kk) * 64 + l * 8 + 4]);
                float xk = (kk == 0) ? xv.x : (kk == 1) ? xv.y : (kk == 2) ? xv.z : xv.w;
                a2[0] += xk * w0.x; a2[1] += xk * w0.y;
                a2[2] += xk * w0.z; a2[3] += xk * w0.w;
                a2[4] += xk * w1.x; a2[5] += xk * w1.y;
                a2[6] += xk * w1.z; a2[7] += xk * w1.w;
            }
        }
        int grow = rowBase + row;
        if (grow < N) {
            __half2 h0 = __floats2half2_rn(a2[0], a2[1]);
            __half2 h1 = __floats2half2_rn(a2[2], a2[3]);
            __half2 h2 = __floats2half2_rn(a2[4], a2[5]);
            __half2 h3 = __floats2half2_rn(a2[6], a2[7]);
            uint4 pk;
            pk.x = *(unsigned int*)&h0;
            pk.y = *(unsigned int*)&h1;
            pk.z = *(unsigned int*)&h2;
            pk.w = *(unsigned int*)&h3;
            *((uint4*)(Hh + (size_t)grow * 64 + l * 8)) = pk;
        }
    } else {
        float* outF = (float*)OutP;
        for (int t2 = lane; t2 < 80; t2 += 64) {
            int ln = t2 / 10;
            int cl = t2 - ln * 10;
            int lrow = wave * 8 + ln;
            float acc = Wb[cl];
#pragma unroll
            for (int k = 0; k < 64; k += 4) {
                float4 xv = *((const float4*)&Xs[lrow * XS_STRIDE + k]);
                float4 wv = *((const float4*)&Ws[cl * 68 + k]);
                acc += xv.x * wv.x + xv.y * wv.y + xv.z * wv.z + xv.w * wv.w;
            }
            int grow = rowBase + lrow;
            if (grow < N) outF[(size_t)grow * 10 + cl] = acc;
        }
    }
}

extern "C" void kernel_launch(void* const* d_in, const int* in_sizes, int n_in,
                              void* d_out, int out_size, void* d_ws, size_t ws_size,
                              hipStream_t stream) {
    const float* x   = (const float*)d_in[0];
    const int*   src = (const int*)d_in[1];
    const int*   dst = (const int*)d_in[2];
    const float* W1  = (const float*)d_in[3];
    const float* b1  = (const float*)d_in[4];
    const float* W2  = (const float*)d_in[5];
    const float* b2  = (const float*)d_in[6];
    const float* W3  = (const float*)d_in[7];
    const float* b3  = (const float*)d_in[8];
    const float* Wfc = (const float*)d_in[9];
    const float* bfc = (const float*)d_in[10];
    float* out = (float*)d_out;
    int N = in_sizes[0] / 64;
    int E = in_sizes[1];
    int P = (E + CHUNK - 1) >> CHUNK_SHIFT;
    int words = (N + 3) / 4;

    char* ws = (char*)d_ws;
    size_t p = 0;
    auto alloc = [&](size_t bytes) -> void* {
        void* r = ws + p;
        p = (p + bytes + 255) & ~(size_t)255;
        return r;
    };
    int*    deg_d = (int*)alloc((size_t)N * 4);
    int*    rp    = (int*)alloc((size_t)N * 4);
    int*    bsum  = (int*)alloc((size_t)THREADS * 4);
    unsigned char* rank = (unsigned char*)alloc((size_t)E);
    int*    col   = (int*)alloc((size_t)E * 4);
    float*  ns    = (float*)alloc((size_t)N * 4);
    float*  nd    = (float*)alloc((size_t)N * 4);
    unsigned int* partS = (unsigned int*)alloc((size_t)P * words * 4);
    unsigned int* partD = (unsigned int*)alloc((size_t)P * words * 4);
    unsigned int* prefD = (unsigned int*)alloc((size_t)P * words * 4);
    __half* bufH  = (__half*)alloc((size_t)N * 64 * 2);
    __half* bufH2 = (__half*)alloc((size_t)N * 64 * 2);
    float*  bufG  = (float*)alloc((size_t)N * 64 * 4);
    unsigned int* counter = (unsigned int*)alloc(4);
    (void)ws_size; (void)n_in; (void)out_size;

    int gFill  = (E + 255) / 256;
    int gP     = (words + 63) / 64;
    int gGemm  = (N + 63) / 64;          // raw-GEMM tiles (64 rows, 1024 thr)
    int gScale = (N * 16 + 255) / 256;   // scale pass (one float4 per thread)
    int gAgg   = (N + 63) / 64;          // agg tiles (64 rows, 512 thr)

    k_hist_gemm<<<2 * P + gGemm, 1024, 0, stream>>>(src, dst, partS, partD, rank,
                                                    counter, E, P, words,
                                                    x, W1, bufG, N);
    k_pre <<<gP, THREADS, 0, stream>>>(partS, partD, prefD, deg_d, ns, nd,
                                       rp, bsum, counter, P, words, N);
    k_fill_scale<<<gFill + gScale, 256, 0, stream>>>(src, dst, rp, bsum, rank, prefD,
                                                     col, E, words, gFill,
                                                     bufG, ns, bufH, N);
    k_agg_gemm<0><<<gAgg, 512, 0, stream>>>((const uint4*)bufH,  rp, bsum, deg_d, col,
                                            nd, ns, b1, W2, nullptr, bufH2, N);
    k_agg_gemm<0><<<gAgg, 512, 0, stream>>>((const uint4*)bufH2, rp, bsum, deg_d, col,
                                            nd, ns, b2, W3, nullptr, bufH, N);
    k_agg_gemm<1><<<gAgg, 512, 0, stream>>>((const uint4*)bufH,  rp, bsum, deg_d, col,
                                            nd, ns, b3, Wfc, bfc, out, N);
}